// Round 1
// baseline (3499.125 us; speedup 1.0000x reference)
//
#include <hip/hip_runtime.h>
#include <math.h>

#define T_TOK 1024
#define H_DIM 2048
#define N_EXP 32
#define TOPK  4
#define F_DIM 768
#define FS_DIM 4096

// ---------------- router: fp32 logits -> softmax -> top4 -> lists ----------------
__global__ __launch_bounds__(256) void router_kernel(
    const float* __restrict__ x, const float* __restrict__ rw,
    const float* __restrict__ sgw,
    float* __restrict__ topw, float* __restrict__ sg,
    int* __restrict__ counts, int* __restrict__ lists)
{
  int t = blockIdx.x; int tid = threadIdx.x;
  int lane = tid & 63, wave = tid >> 6;
  float acc[N_EXP];
  #pragma unroll
  for (int e = 0; e < N_EXP; e++) acc[e] = 0.f;
  float accs = 0.f;
  const float* xr = x + (size_t)t * H_DIM;
  for (int h = tid; h < H_DIM; h += 256) {
    float xv = xr[h];
    accs += xv * sgw[h];
    #pragma unroll
    for (int e = 0; e < N_EXP; e++) acc[e] += xv * rw[e * H_DIM + h];
  }
  __shared__ float red[4][N_EXP];
  __shared__ float reds[4];
  __shared__ float logits[N_EXP];
  #pragma unroll
  for (int e = 0; e < N_EXP; e++) {
    float v = acc[e];
    for (int off = 32; off; off >>= 1) v += __shfl_down(v, off, 64);
    if (lane == 0) red[wave][e] = v;
  }
  {
    float v = accs;
    for (int off = 32; off; off >>= 1) v += __shfl_down(v, off, 64);
    if (lane == 0) reds[wave] = v;
  }
  __syncthreads();
  if (tid < N_EXP) logits[tid] = red[0][tid] + red[1][tid] + red[2][tid] + red[3][tid];
  __syncthreads();
  if (tid == 0) {
    float m = -1e30f;
    #pragma unroll
    for (int e = 0; e < N_EXP; e++) m = fmaxf(m, logits[e]);
    float p[N_EXP];
    #pragma unroll
    for (int e = 0; e < N_EXP; e++) p[e] = expf(logits[e] - m);
    int ids[TOPK]; float vs[TOPK]; float wsum = 0.f;
    #pragma unroll
    for (int k = 0; k < TOPK; k++) {
      int best = 0; float bv = -1.f;
      for (int e = 0; e < N_EXP; e++) {
        if (p[e] > bv) { bv = p[e]; best = e; }
      }
      ids[k] = best; vs[k] = bv; wsum += bv; p[best] = -2.f;
    }
    float inv = 1.f / wsum;
    float sgs = reds[0] + reds[1] + reds[2] + reds[3];
    sg[t] = 1.f / (1.f + expf(-sgs));
    #pragma unroll
    for (int k = 0; k < TOPK; k++) {
      int slot = t * TOPK + k;
      topw[slot] = vs[k] * inv;
      int pos = atomicAdd(&counts[ids[k]], 1);
      lists[ids[k] * T_TOK + pos] = slot;
    }
  }
}

// ---------------- gate/up + SiLU*up (dual GEMM), 64x64 tile, BK=16 ----------------
// GATHER=true : per-expert, rows gathered via lists (slot/4 = token), B = [E,H,F]
// GATHER=false: shared expert, rows = tokens,                        B = [H,FS]
template<bool GATHER>
__global__ __launch_bounds__(256) void gateup_kernel(
    const float* __restrict__ X,
    const float* __restrict__ Bg_, const float* __restrict__ Bu_,
    float* __restrict__ Cact,
    const int* __restrict__ lists, const int* __restrict__ counts,
    int N)
{
  int e, count;
  const int* lb = nullptr;
  if (GATHER) { e = blockIdx.z; count = counts[e]; lb = lists + e * T_TOK; }
  else        { e = 0; count = T_TOK; }
  int mt = blockIdx.x * 64;
  if (mt >= count) return;
  int fb = blockIdx.y * 64;
  const float* Bg = Bg_ + (size_t)e * H_DIM * N;
  const float* Bu = Bu_ + (size_t)e * H_DIM * N;
  int tid = threadIdx.x;

  __shared__ float sA[16][64];
  __shared__ float sBg[16][64];
  __shared__ float sBu[16][64];

  int ar = mt + (tid >> 2);
  int arc = ar < count ? ar : (count - 1);
  int tok;
  if (GATHER) tok = lb[arc] >> 2; else tok = arc;
  const float* aptr = X + (size_t)tok * H_DIM + ((tid & 3) << 2);
  int bk = tid >> 4, bc = (tid & 15) << 2;
  const float* bgp = Bg + (size_t)bk * N + fb + bc;
  const float* bup = Bu + (size_t)bk * N + fb + bc;

  float ag[4][4] = {}; float au[4][4] = {};
  int mrow = (tid >> 4) << 2, ncol = (tid & 15) << 2;

  for (int k0 = 0; k0 < H_DIM; k0 += 16) {
    float4 av = *(const float4*)(aptr + k0);
    float4 gv = *(const float4*)(bgp + (size_t)k0 * N);
    float4 uv = *(const float4*)(bup + (size_t)k0 * N);
    __syncthreads();
    int kk4 = (tid & 3) << 2;
    sA[kk4 + 0][tid >> 2] = av.x; sA[kk4 + 1][tid >> 2] = av.y;
    sA[kk4 + 2][tid >> 2] = av.z; sA[kk4 + 3][tid >> 2] = av.w;
    *(float4*)&sBg[bk][bc] = gv;
    *(float4*)&sBu[bk][bc] = uv;
    __syncthreads();
    #pragma unroll
    for (int kk = 0; kk < 16; kk++) {
      float4 a = *(const float4*)&sA[kk][mrow];
      float4 g = *(const float4*)&sBg[kk][ncol];
      float4 u = *(const float4*)&sBu[kk][ncol];
      float aa[4] = {a.x, a.y, a.z, a.w};
      float gg[4] = {g.x, g.y, g.z, g.w};
      float uu[4] = {u.x, u.y, u.z, u.w};
      #pragma unroll
      for (int i = 0; i < 4; i++)
        #pragma unroll
        for (int j = 0; j < 4; j++) {
          ag[i][j] += aa[i] * gg[j];
          au[i][j] += aa[i] * uu[j];
        }
    }
  }
  #pragma unroll
  for (int i = 0; i < 4; i++) {
    int r = mt + mrow + i;
    if (r < count) {
      size_t rowo;
      if (GATHER) rowo = (size_t)lb[r] * N;
      else        rowo = (size_t)r * N;
      #pragma unroll
      for (int j = 0; j < 4; j++) {
        float g = ag[i][j];
        float a = g / (1.f + expf(-g)) * au[i][j];
        Cact[rowo + fb + ncol + j] = a;
      }
    }
  }
}

// ---------------- down-proj, 64x64 tile, BK=16 ----------------
// EXPERT=true : A = act[slots,F] gathered, B = [E,F,H], scale topw[slot], atomicAdd
// EXPERT=false: A = act_s[T,FS],           B = [FS,H],  scale sg[t], plain add
template<bool EXPERT>
__global__ __launch_bounds__(256) void down_kernel(
    const float* __restrict__ Aact,
    const float* __restrict__ Bd_,
    float* __restrict__ out,
    const float* __restrict__ rowscale,
    const int* __restrict__ lists, const int* __restrict__ counts,
    int Kd)
{
  int e, count;
  const int* lb = nullptr;
  if (EXPERT) { e = blockIdx.z; count = counts[e]; lb = lists + e * T_TOK; }
  else        { e = 0; count = T_TOK; }
  int mt = blockIdx.x * 64;
  if (mt >= count) return;
  int nb = blockIdx.y * 64;
  const float* Bd = Bd_ + (size_t)e * F_DIM * H_DIM;
  int tid = threadIdx.x;
  __shared__ float sA[16][64];
  __shared__ float sB[16][64];
  int ar = mt + (tid >> 2);
  int arc = ar < count ? ar : (count - 1);
  int arow;
  if (EXPERT) arow = lb[arc]; else arow = arc;
  const float* aptr = Aact + (size_t)arow * Kd + ((tid & 3) << 2);
  int bk = tid >> 4, bc = (tid & 15) << 2;
  const float* bp = Bd + (size_t)bk * H_DIM + nb + bc;
  float acc[4][4] = {};
  int mrow = (tid >> 4) << 2, ncol = (tid & 15) << 2;
  for (int k0 = 0; k0 < Kd; k0 += 16) {
    float4 av = *(const float4*)(aptr + k0);
    float4 bv = *(const float4*)(bp + (size_t)k0 * H_DIM);
    __syncthreads();
    int kk4 = (tid & 3) << 2;
    sA[kk4 + 0][tid >> 2] = av.x; sA[kk4 + 1][tid >> 2] = av.y;
    sA[kk4 + 2][tid >> 2] = av.z; sA[kk4 + 3][tid >> 2] = av.w;
    *(float4*)&sB[bk][bc] = bv;
    __syncthreads();
    #pragma unroll
    for (int kk = 0; kk < 16; kk++) {
      float4 a = *(const float4*)&sA[kk][mrow];
      float4 b = *(const float4*)&sB[kk][ncol];
      float aa[4] = {a.x, a.y, a.z, a.w};
      float bb[4] = {b.x, b.y, b.z, b.w};
      #pragma unroll
      for (int i = 0; i < 4; i++)
        #pragma unroll
        for (int j = 0; j < 4; j++)
          acc[i][j] += aa[i] * bb[j];
    }
  }
  #pragma unroll
  for (int i = 0; i < 4; i++) {
    int r = mt + mrow + i;
    if (r < count) {
      if (EXPERT) {
        int slot = lb[r]; int t = slot >> 2; float w = rowscale[slot];
        #pragma unroll
        for (int j = 0; j < 4; j++)
          atomicAdd(&out[(size_t)t * H_DIM + nb + ncol + j], w * acc[i][j]);
      } else {
        float w = rowscale[r];
        #pragma unroll
        for (int j = 0; j < 4; j++)
          out[(size_t)r * H_DIM + nb + ncol + j] += w * acc[i][j];
      }
    }
  }
}

extern "C" void kernel_launch(void* const* d_in, const int* in_sizes, int n_in,
                              void* d_out, int out_size, void* d_ws, size_t ws_size,
                              hipStream_t stream) {
  const float* x   = (const float*)d_in[0];
  const float* rw  = (const float*)d_in[1];
  const float* wg  = (const float*)d_in[2];
  const float* wu  = (const float*)d_in[3];
  const float* wd  = (const float*)d_in[4];
  const float* swg = (const float*)d_in[5];
  const float* swu = (const float*)d_in[6];
  const float* swd = (const float*)d_in[7];
  const float* sgw = (const float*)d_in[8];
  float* out = (float*)d_out;
  char* ws = (char*)d_ws;

  size_t off = 0;
  int*   counts = (int*)(ws + off); off += 128;
  int*   lists  = (int*)(ws + off); off += (size_t)N_EXP * T_TOK * 4;        // 128 KB
  float* topw   = (float*)(ws + off); off += (size_t)T_TOK * TOPK * 4;      // 16 KB
  float* sg     = (float*)(ws + off); off += (size_t)T_TOK * 4;             // 4 KB
  float* act    = (float*)(ws + off); off += (size_t)T_TOK * TOPK * F_DIM * 4;  // 12.6 MB
  float* acts   = (float*)(ws + off); off += (size_t)T_TOK * FS_DIM * 4;        // 16.8 MB

  hipMemsetAsync(counts, 0, 128, stream);
  hipMemsetAsync(out, 0, (size_t)T_TOK * H_DIM * sizeof(float), stream);

  router_kernel<<<T_TOK, 256, 0, stream>>>(x, rw, sgw, topw, sg, counts, lists);

  dim3 g1(T_TOK / 64, F_DIM / 64, N_EXP);
  gateup_kernel<true><<<g1, 256, 0, stream>>>(x, wg, wu, act, lists, counts, F_DIM);

  dim3 g2(T_TOK / 64, FS_DIM / 64, 1);
  gateup_kernel<false><<<g2, 256, 0, stream>>>(x, swg, swu, acts, nullptr, nullptr, FS_DIM);

  dim3 g3(T_TOK / 64, H_DIM / 64, N_EXP);
  down_kernel<true><<<g3, 256, 0, stream>>>(act, wd, out, topw, lists, counts, F_DIM);

  dim3 g4(T_TOK / 64, H_DIM / 64, 1);
  down_kernel<false><<<g4, 256, 0, stream>>>(acts, swd, out, sg, nullptr, nullptr, FS_DIM);
}

// Round 2
// 1354.801 us; speedup vs baseline: 2.5828x; 2.5828x over previous
//
#include <hip/hip_runtime.h>
#include <math.h>

#define T_TOK 1024
#define H_DIM 2048
#define N_EXP 32
#define TOPK  4
#define F_DIM 768
#define FS_DIM 4096

typedef __bf16 bf16;
typedef __attribute__((ext_vector_type(4))) __bf16 bf16x4;
typedef __attribute__((ext_vector_type(8))) __bf16 bf16x8;
typedef __attribute__((ext_vector_type(4))) float f32x4;

__device__ __forceinline__ bf16x4 cvt4(f32x4 v) {
  bf16x4 r; r[0] = (bf16)v[0]; r[1] = (bf16)v[1]; r[2] = (bf16)v[2]; r[3] = (bf16)v[3];
  return r;
}

// ---------------- router: fp32 logits -> softmax -> top4 -> lists ----------------
__global__ __launch_bounds__(256) void router_kernel(
    const float* __restrict__ x, const float* __restrict__ rw,
    const float* __restrict__ sgw,
    float* __restrict__ topw, float* __restrict__ sg,
    int* __restrict__ counts, int* __restrict__ lists)
{
  int t = blockIdx.x; int tid = threadIdx.x;
  int lane = tid & 63, wave = tid >> 6;
  float acc[N_EXP];
  #pragma unroll
  for (int e = 0; e < N_EXP; e++) acc[e] = 0.f;
  float accs = 0.f;
  const float* xr = x + (size_t)t * H_DIM;
  for (int h = tid; h < H_DIM; h += 256) {
    float xv = xr[h];
    accs += xv * sgw[h];
    #pragma unroll
    for (int e = 0; e < N_EXP; e++) acc[e] += xv * rw[e * H_DIM + h];
  }
  __shared__ float red[4][N_EXP];
  __shared__ float reds[4];
  __shared__ float logits[N_EXP];
  #pragma unroll
  for (int e = 0; e < N_EXP; e++) {
    float v = acc[e];
    for (int off = 32; off; off >>= 1) v += __shfl_down(v, off, 64);
    if (lane == 0) red[wave][e] = v;
  }
  {
    float v = accs;
    for (int off = 32; off; off >>= 1) v += __shfl_down(v, off, 64);
    if (lane == 0) reds[wave] = v;
  }
  __syncthreads();
  if (tid < N_EXP) logits[tid] = red[0][tid] + red[1][tid] + red[2][tid] + red[3][tid];
  __syncthreads();
  if (tid == 0) {
    float m = -1e30f;
    #pragma unroll
    for (int e = 0; e < N_EXP; e++) m = fmaxf(m, logits[e]);
    float p[N_EXP];
    #pragma unroll
    for (int e = 0; e < N_EXP; e++) p[e] = expf(logits[e] - m);
    int ids[TOPK]; float vs[TOPK]; float wsum = 0.f;
    #pragma unroll
    for (int k = 0; k < TOPK; k++) {
      int best = 0; float bv = -1.f;
      for (int e = 0; e < N_EXP; e++) {
        if (p[e] > bv) { bv = p[e]; best = e; }
      }
      ids[k] = best; vs[k] = bv; wsum += bv; p[best] = -2.f;
    }
    float inv = 1.f / wsum;
    float sgs = reds[0] + reds[1] + reds[2] + reds[3];
    sg[t] = 1.f / (1.f + expf(-sgs));
    #pragma unroll
    for (int k = 0; k < TOPK; k++) {
      int slot = t * TOPK + k;
      topw[slot] = vs[k] * inv;
      int pos = atomicAdd(&counts[ids[k]], 1);
      lists[ids[k] * T_TOK + pos] = slot;
    }
  }
}

// ---------------- gate/up dual GEMM + SwiGLU, MFMA bf16, 128x64 tile, BK=64 ----------
// GATHER=true : rows gathered via lists (slot>>2 = token), W = [E,H,N]
// GATHER=false: rows = tokens, W = [H,N]
template<bool GATHER>
__global__ __launch_bounds__(256) void gateup_mfma(
    const float* __restrict__ X,
    const float* __restrict__ Wg_, const float* __restrict__ Wu_,
    bf16* __restrict__ Cact,
    const int* __restrict__ lists, const int* __restrict__ counts, int N)
{
  int e, count; const int* lb = nullptr;
  if (GATHER) { e = blockIdx.z; count = counts[e]; lb = lists + e * T_TOK; }
  else        { e = 0; count = T_TOK; }
  int mt = blockIdx.x * 128;
  if (mt >= count) return;
  int fb = blockIdx.y * 64;
  const float* Wg = Wg_ + (size_t)e * H_DIM * N;
  const float* Wu = Wu_ + (size_t)e * H_DIM * N;
  int tid = threadIdx.x;
  int lane = tid & 63, wid = tid >> 6;
  int wr = wid >> 1, wc = wid & 1;   // wave tile: 64 rows x 32 cols

  __shared__ alignas(16) bf16 sA [128][72];  // [m][k], +8 pad (144B rows, 16B aligned)
  __shared__ alignas(16) bf16 sBg[64][72];   // [n][k] transposed
  __shared__ alignas(16) bf16 sBu[64][72];

  int tokr[8];
  #pragma unroll
  for (int i = 0; i < 8; i++) {
    int r = mt + i * 16 + (tid >> 4);
    int rc = r < count ? r : count - 1;
    tokr[i] = GATHER ? (lb[rc] >> 2) : rc;
  }
  int acol = (tid & 15) * 4;  // A: col-4-group within K-tile
  int k4 = tid >> 4;          // B: k-quad 0..15
  int ng = tid & 15;          // B: n-quad 0..15

  f32x4 accg[4][2], accu[4][2];
  #pragma unroll
  for (int m = 0; m < 4; m++)
    #pragma unroll
    for (int n = 0; n < 2; n++) {
      accg[m][n] = (f32x4){0.f, 0.f, 0.f, 0.f};
      accu[m][n] = (f32x4){0.f, 0.f, 0.f, 0.f};
    }

  for (int k0 = 0; k0 < H_DIM; k0 += 64) {
    f32x4 av[8];
    #pragma unroll
    for (int i = 0; i < 8; i++)
      av[i] = *(const f32x4*)(X + (size_t)tokr[i] * H_DIM + k0 + acol);
    f32x4 gv[4], uv[4];
    #pragma unroll
    for (int r = 0; r < 4; r++) {
      size_t ro = (size_t)(k0 + k4 * 4 + r) * N + fb + ng * 4;
      gv[r] = *(const f32x4*)(Wg + ro);
      uv[r] = *(const f32x4*)(Wu + ro);
    }
    __syncthreads();
    #pragma unroll
    for (int i = 0; i < 8; i++)
      *(bf16x4*)&sA[i * 16 + (tid >> 4)][acol] = cvt4(av[i]);
    #pragma unroll
    for (int i = 0; i < 4; i++) {
      bf16x4 tg, tu;
      tg[0] = (bf16)gv[0][i]; tg[1] = (bf16)gv[1][i]; tg[2] = (bf16)gv[2][i]; tg[3] = (bf16)gv[3][i];
      tu[0] = (bf16)uv[0][i]; tu[1] = (bf16)uv[1][i]; tu[2] = (bf16)uv[2][i]; tu[3] = (bf16)uv[3][i];
      *(bf16x4*)&sBg[ng * 4 + i][k4 * 4] = tg;
      *(bf16x4*)&sBu[ng * 4 + i][k4 * 4] = tu;
    }
    __syncthreads();
    #pragma unroll
    for (int kk = 0; kk < 2; kk++) {
      bf16x8 af[4];
      #pragma unroll
      for (int m = 0; m < 4; m++)
        af[m] = *(const bf16x8*)&sA[wr * 64 + m * 16 + (lane & 15)][kk * 32 + (lane >> 4) * 8];
      #pragma unroll
      for (int n = 0; n < 2; n++) {
        int nr = wc * 32 + n * 16 + (lane & 15);
        bf16x8 bg = *(const bf16x8*)&sBg[nr][kk * 32 + (lane >> 4) * 8];
        bf16x8 bu = *(const bf16x8*)&sBu[nr][kk * 32 + (lane >> 4) * 8];
        #pragma unroll
        for (int m = 0; m < 4; m++) {
          accg[m][n] = __builtin_amdgcn_mfma_f32_16x16x32_bf16(af[m], bg, accg[m][n], 0, 0, 0);
          accu[m][n] = __builtin_amdgcn_mfma_f32_16x16x32_bf16(af[m], bu, accu[m][n], 0, 0, 0);
        }
      }
    }
  }
  #pragma unroll
  for (int m = 0; m < 4; m++) {
    #pragma unroll
    for (int q = 0; q < 4; q++) {
      int gr = mt + wr * 64 + m * 16 + (lane >> 4) * 4 + q;
      if (gr < count) {
        size_t rowo = (GATHER ? (size_t)lb[gr] : (size_t)gr) * N;
        #pragma unroll
        for (int n = 0; n < 2; n++) {
          float g = accg[m][n][q], u = accu[m][n][q];
          float a = g / (1.f + __expf(-g)) * u;
          Cact[rowo + fb + wc * 32 + n * 16 + (lane & 15)] = (bf16)a;
        }
      }
    }
  }
}

// ---------------- down-proj, MFMA bf16, 128x64 tile, BK=64 ----------------
// EXPERT=true : A = act[slots][F] gathered, W = [E,F,H], scale topw[slot], atomicAdd
// EXPERT=false: A = acts[T][FS],            W = [FS,H],  scale sg[t],      atomicAdd
template<bool EXPERT>
__global__ __launch_bounds__(256) void down_mfma(
    const bf16* __restrict__ Aact, const float* __restrict__ Wd_,
    float* __restrict__ out, const float* __restrict__ rowscale,
    const int* __restrict__ lists, const int* __restrict__ counts, int Kd)
{
  int e, count; const int* lb = nullptr;
  if (EXPERT) { e = blockIdx.z; count = counts[e]; lb = lists + e * T_TOK; }
  else        { e = 0; count = T_TOK; }
  int mt = blockIdx.x * 128;
  if (mt >= count) return;
  int nb = blockIdx.y * 64;
  const float* Wd = Wd_ + (size_t)e * F_DIM * H_DIM;
  int tid = threadIdx.x;
  int lane = tid & 63, wid = tid >> 6;
  int wr = wid >> 1, wc = wid & 1;

  __shared__ alignas(16) bf16 sA[128][72];
  __shared__ alignas(16) bf16 sB[64][72];   // [n][k] transposed

  int arow[4];
  #pragma unroll
  for (int i = 0; i < 4; i++) {
    int r = mt + i * 32 + (tid >> 3);
    int rc = r < count ? r : count - 1;
    arow[i] = EXPERT ? lb[rc] : rc;
  }
  int c8 = (tid & 7) * 8;     // A: 8-elem group within K-tile
  int k4 = tid >> 4, ng = tid & 15;

  f32x4 acc[4][2];
  #pragma unroll
  for (int m = 0; m < 4; m++)
    #pragma unroll
    for (int n = 0; n < 2; n++)
      acc[m][n] = (f32x4){0.f, 0.f, 0.f, 0.f};

  for (int k0 = 0; k0 < Kd; k0 += 64) {
    uint4 avv[4];
    #pragma unroll
    for (int i = 0; i < 4; i++)
      avv[i] = *(const uint4*)(Aact + (size_t)arow[i] * Kd + k0 + c8);
    f32x4 bv[4];
    #pragma unroll
    for (int r = 0; r < 4; r++)
      bv[r] = *(const f32x4*)(Wd + (size_t)(k0 + k4 * 4 + r) * H_DIM + nb + ng * 4);
    __syncthreads();
    #pragma unroll
    for (int i = 0; i < 4; i++)
      *(uint4*)&sA[i * 32 + (tid >> 3)][c8] = avv[i];
    #pragma unroll
    for (int i = 0; i < 4; i++) {
      bf16x4 t;
      t[0] = (bf16)bv[0][i]; t[1] = (bf16)bv[1][i]; t[2] = (bf16)bv[2][i]; t[3] = (bf16)bv[3][i];
      *(bf16x4*)&sB[ng * 4 + i][k4 * 4] = t;
    }
    __syncthreads();
    #pragma unroll
    for (int kk = 0; kk < 2; kk++) {
      bf16x8 af[4];
      #pragma unroll
      for (int m = 0; m < 4; m++)
        af[m] = *(const bf16x8*)&sA[wr * 64 + m * 16 + (lane & 15)][kk * 32 + (lane >> 4) * 8];
      #pragma unroll
      for (int n = 0; n < 2; n++) {
        bf16x8 bfv = *(const bf16x8*)&sB[wc * 32 + n * 16 + (lane & 15)][kk * 32 + (lane >> 4) * 8];
        #pragma unroll
        for (int m = 0; m < 4; m++)
          acc[m][n] = __builtin_amdgcn_mfma_f32_16x16x32_bf16(af[m], bfv, acc[m][n], 0, 0, 0);
      }
    }
  }
  #pragma unroll
  for (int m = 0; m < 4; m++) {
    #pragma unroll
    for (int q = 0; q < 4; q++) {
      int gr = mt + wr * 64 + m * 16 + (lane >> 4) * 4 + q;
      if (gr < count) {
        float w; size_t to;
        if (EXPERT) { int slot = lb[gr]; w = rowscale[slot]; to = (size_t)(slot >> 2) * H_DIM; }
        else        { w = rowscale[gr]; to = (size_t)gr * H_DIM; }
        #pragma unroll
        for (int n = 0; n < 2; n++)
          atomicAdd(&out[to + nb + wc * 32 + n * 16 + (lane & 15)], w * acc[m][n][q]);
      }
    }
  }
}

extern "C" void kernel_launch(void* const* d_in, const int* in_sizes, int n_in,
                              void* d_out, int out_size, void* d_ws, size_t ws_size,
                              hipStream_t stream) {
  const float* x   = (const float*)d_in[0];
  const float* rw  = (const float*)d_in[1];
  const float* wg  = (const float*)d_in[2];
  const float* wu  = (const float*)d_in[3];
  const float* wd  = (const float*)d_in[4];
  const float* swg = (const float*)d_in[5];
  const float* swu = (const float*)d_in[6];
  const float* swd = (const float*)d_in[7];
  const float* sgw = (const float*)d_in[8];
  float* out = (float*)d_out;
  char* ws = (char*)d_ws;

  size_t off = 0;
  int*   counts = (int*)(ws + off); off += 128;
  int*   lists  = (int*)(ws + off); off += (size_t)N_EXP * T_TOK * 4;
  float* topw   = (float*)(ws + off); off += (size_t)T_TOK * TOPK * 4;
  float* sg     = (float*)(ws + off); off += (size_t)T_TOK * 4;
  bf16*  act    = (bf16*)(ws + off); off += (size_t)T_TOK * TOPK * F_DIM * 2;  // 6.3 MB
  bf16*  acts   = (bf16*)(ws + off); off += (size_t)T_TOK * FS_DIM * 2;        // 8.4 MB

  hipMemsetAsync(counts, 0, 128, stream);
  hipMemsetAsync(out, 0, (size_t)T_TOK * H_DIM * sizeof(float), stream);

  router_kernel<<<T_TOK, 256, 0, stream>>>(x, rw, sgw, topw, sg, counts, lists);

  // expert counts <= T_TOK, so M-blocks per expert <= T_TOK/128 = 8
  gateup_mfma<true><<<dim3(T_TOK / 128, F_DIM / 64, N_EXP), 256, 0, stream>>>(
      x, wg, wu, act, lists, counts, F_DIM);
  gateup_mfma<false><<<dim3(T_TOK / 128, FS_DIM / 64, 1), 256, 0, stream>>>(
      x, swg, swu, acts, nullptr, nullptr, FS_DIM);
  down_mfma<true><<<dim3(T_TOK / 128, H_DIM / 64, N_EXP), 256, 0, stream>>>(
      act, wd, out, topw, lists, counts, F_DIM);
  down_mfma<false><<<dim3(T_TOK / 128, H_DIM / 64, 1), 256, 0, stream>>>(
      acts, swd, out, sg, nullptr, nullptr, FS_DIM);
}

// Round 4
// 1049.280 us; speedup vs baseline: 3.3348x; 1.2912x over previous
//
#include <hip/hip_runtime.h>
#include <math.h>

#define T_TOK 1024
#define H_DIM 2048
#define N_EXP 32
#define TOPK  4
#define F_DIM 768
#define FS_DIM 4096
#define FS_HALF 2048

typedef __bf16 bf16;
typedef __attribute__((ext_vector_type(4))) __bf16 bf16x4;
typedef __attribute__((ext_vector_type(8))) __bf16 bf16x8;
typedef __attribute__((ext_vector_type(4))) float f32x4;

__device__ __forceinline__ bf16x4 cvt4(f32x4 v) {
  bf16x4 r; r[0] = (bf16)v[0]; r[1] = (bf16)v[1]; r[2] = (bf16)v[2]; r[3] = (bf16)v[3];
  return r;
}

// ---------------- router: fp32 logits -> softmax -> top4 -> lists ----------------
__global__ __launch_bounds__(256) void router_kernel(
    const float* __restrict__ x, const float* __restrict__ rw,
    const float* __restrict__ sgw,
    float* __restrict__ topw, float* __restrict__ sg,
    int* __restrict__ counts, int* __restrict__ lists)
{
  int t = blockIdx.x; int tid = threadIdx.x;
  int lane = tid & 63, wave = tid >> 6;
  float acc[N_EXP];
  #pragma unroll
  for (int e = 0; e < N_EXP; e++) acc[e] = 0.f;
  float accs = 0.f;
  const float* xr = x + (size_t)t * H_DIM;
  for (int h = tid; h < H_DIM; h += 256) {
    float xv = xr[h];
    accs += xv * sgw[h];
    #pragma unroll
    for (int e = 0; e < N_EXP; e++) acc[e] += xv * rw[e * H_DIM + h];
  }
  __shared__ float red[4][N_EXP];
  __shared__ float reds[4];
  __shared__ float logits[N_EXP];
  #pragma unroll
  for (int e = 0; e < N_EXP; e++) {
    float v = acc[e];
    for (int off = 32; off; off >>= 1) v += __shfl_down(v, off, 64);
    if (lane == 0) red[wave][e] = v;
  }
  {
    float v = accs;
    for (int off = 32; off; off >>= 1) v += __shfl_down(v, off, 64);
    if (lane == 0) reds[wave] = v;
  }
  __syncthreads();
  if (tid < N_EXP) logits[tid] = red[0][tid] + red[1][tid] + red[2][tid] + red[3][tid];
  __syncthreads();
  if (tid == 0) {
    float m = -1e30f;
    #pragma unroll
    for (int e = 0; e < N_EXP; e++) m = fmaxf(m, logits[e]);
    float p[N_EXP];
    #pragma unroll
    for (int e = 0; e < N_EXP; e++) p[e] = expf(logits[e] - m);
    int ids[TOPK]; float vs[TOPK]; float wsum = 0.f;
    #pragma unroll
    for (int k = 0; k < TOPK; k++) {
      int best = 0; float bv = -1.f;
      for (int e = 0; e < N_EXP; e++) {
        if (p[e] > bv) { bv = p[e]; best = e; }
      }
      ids[k] = best; vs[k] = bv; wsum += bv; p[best] = -2.f;
    }
    float inv = 1.f / wsum;
    float sgs = reds[0] + reds[1] + reds[2] + reds[3];
    sg[t] = 1.f / (1.f + expf(-sgs));
    #pragma unroll
    for (int k = 0; k < TOPK; k++) {
      int slot = t * TOPK + k;
      topw[slot] = vs[k] * inv;
      int pos = atomicAdd(&counts[ids[k]], 1);
      lists[ids[k] * T_TOK + pos] = slot;
    }
  }
}

// ---------------- gate/up dual GEMM + SwiGLU, MFMA bf16, 64x64 tile, BK=64 ----------
// GATHER=true : rows via lists (slot>>2 = token), W base indexed by blockIdx.z, ldb==Nout
// GATHER=false: rows = tokens; W pre-offset by caller (column half), row stride ldb
template<bool GATHER>
__global__ __launch_bounds__(256) void gateup_mfma(
    const float* __restrict__ X,
    const float* __restrict__ Wg, const float* __restrict__ Wu,
    bf16* __restrict__ Cact,
    const int* __restrict__ lists, const int* __restrict__ counts,
    int Nout, int ldb)
{
  int count; const int* lb = nullptr;
  if (GATHER) {
    int e = blockIdx.z; count = counts[e]; lb = lists + e * T_TOK;
    Wg += (size_t)e * H_DIM * ldb; Wu += (size_t)e * H_DIM * ldb;
  } else {
    count = T_TOK;
  }
  int mt = blockIdx.x * 64;
  if (mt >= count) return;
  int fb = blockIdx.y * 64;
  int tid = threadIdx.x;
  int lane = tid & 63, wid = tid >> 6;
  int wr = wid >> 1, wc = wid & 1;   // wave tile: 32 rows x 32 cols

  __shared__ alignas(16) bf16 sA [64][72];
  __shared__ alignas(16) bf16 sBg[64][72];   // [n][k] transposed
  __shared__ alignas(16) bf16 sBu[64][72];

  {
    int r = mt + (tid >> 2);
    int rc = r < count ? r : count - 1;
    int tok = GATHER ? (lb[rc] >> 2) : rc;
    X += (size_t)tok * H_DIM + ((tid & 3) << 4);
  }
  int k4 = tid >> 4;          // B: k-quad 0..15
  int ng = tid & 15;          // B: n-quad 0..15

  f32x4 accg[2][2], accu[2][2];
  #pragma unroll
  for (int m = 0; m < 2; m++)
    #pragma unroll
    for (int n = 0; n < 2; n++) {
      accg[m][n] = (f32x4){0.f, 0.f, 0.f, 0.f};
      accu[m][n] = (f32x4){0.f, 0.f, 0.f, 0.f};
    }

  f32x4 av[4], gv[4], uv[4];
  #define LOAD_T(k0) do {                                             \
    _Pragma("unroll")                                                 \
    for (int i = 0; i < 4; i++)                                       \
      av[i] = *(const f32x4*)(X + (k0) + i * 4);                      \
    _Pragma("unroll")                                                 \
    for (int r = 0; r < 4; r++) {                                     \
      size_t ro = (size_t)((k0) + k4 * 4 + r) * ldb + fb + ng * 4;    \
      gv[r] = *(const f32x4*)(Wg + ro);                               \
      uv[r] = *(const f32x4*)(Wu + ro);                               \
    } } while (0)

  LOAD_T(0);
  const int NT = H_DIM / 64;
  for (int t = 0; t < NT; t++) {
    __syncthreads();
    #pragma unroll
    for (int i = 0; i < 4; i++)
      *(bf16x4*)&sA[tid >> 2][((tid & 3) << 4) + i * 4] = cvt4(av[i]);
    #pragma unroll
    for (int i = 0; i < 4; i++) {
      bf16x4 tg, tu;
      tg[0] = (bf16)gv[0][i]; tg[1] = (bf16)gv[1][i]; tg[2] = (bf16)gv[2][i]; tg[3] = (bf16)gv[3][i];
      tu[0] = (bf16)uv[0][i]; tu[1] = (bf16)uv[1][i]; tu[2] = (bf16)uv[2][i]; tu[3] = (bf16)uv[3][i];
      *(bf16x4*)&sBg[ng * 4 + i][k4 * 4] = tg;
      *(bf16x4*)&sBu[ng * 4 + i][k4 * 4] = tu;
    }
    __syncthreads();
    if (t + 1 < NT) LOAD_T((t + 1) * 64);
    #pragma unroll
    for (int kk = 0; kk < 2; kk++) {
      bf16x8 af[2];
      #pragma unroll
      for (int m = 0; m < 2; m++)
        af[m] = *(const bf16x8*)&sA[wr * 32 + m * 16 + (lane & 15)][kk * 32 + (lane >> 4) * 8];
      #pragma unroll
      for (int n = 0; n < 2; n++) {
        int nr = wc * 32 + n * 16 + (lane & 15);
        bf16x8 bg = *(const bf16x8*)&sBg[nr][kk * 32 + (lane >> 4) * 8];
        bf16x8 bu = *(const bf16x8*)&sBu[nr][kk * 32 + (lane >> 4) * 8];
        #pragma unroll
        for (int m = 0; m < 2; m++) {
          accg[m][n] = __builtin_amdgcn_mfma_f32_16x16x32_bf16(af[m], bg, accg[m][n], 0, 0, 0);
          accu[m][n] = __builtin_amdgcn_mfma_f32_16x16x32_bf16(af[m], bu, accu[m][n], 0, 0, 0);
        }
      }
    }
  }
  #undef LOAD_T
  #pragma unroll
  for (int m = 0; m < 2; m++) {
    #pragma unroll
    for (int q = 0; q < 4; q++) {
      int gr = mt + wr * 32 + m * 16 + (lane >> 4) * 4 + q;
      if (gr < count) {
        size_t rowo = (GATHER ? (size_t)lb[gr] : (size_t)gr) * Nout;
        #pragma unroll
        for (int n = 0; n < 2; n++) {
          float g = accg[m][n][q], u = accu[m][n][q];
          float a = g / (1.f + __expf(-g)) * u;
          Cact[rowo + fb + wc * 32 + n * 16 + (lane & 15)] = (bf16)a;
        }
      }
    }
  }
}

// ---------------- down-proj, MFMA bf16, 64x64 tile, BK=64 ----------------
// MODE 0: expert — A = act[slot][F_DIM] gathered, W indexed by blockIdx.z,
//         writes dstb[slot][H] (bf16, unscaled)
// MODE 1: shared half0 — A = acts[t][FS_HALF], W pre-offset, out = sg*acc (store)
// MODE 2: shared half1 — same, out += sg*acc (RMW)
template<int MODE>
__global__ __launch_bounds__(256) void down_mfma(
    const bf16* __restrict__ Aact, const float* __restrict__ Wd,
    bf16* __restrict__ dstb, float* __restrict__ dstf,
    const float* __restrict__ sg,
    const int* __restrict__ lists, const int* __restrict__ counts, int Kd)
{
  int count; const int* lb = nullptr;
  if (MODE == 0) {
    int e = blockIdx.z; count = counts[e]; lb = lists + e * T_TOK;
    Wd += (size_t)e * F_DIM * H_DIM;
  } else {
    count = T_TOK;
  }
  int mt = blockIdx.x * 64;
  if (mt >= count) return;
  int nb = blockIdx.y * 64;
  int tid = threadIdx.x;
  int lane = tid & 63, wid = tid >> 6;
  int wr = wid >> 1, wc = wid & 1;

  __shared__ alignas(16) bf16 sA[64][72];
  __shared__ alignas(16) bf16 sB[64][72];   // [n][k] transposed

  {
    int r = mt + (tid >> 2);
    int rc = r < count ? r : count - 1;
    int arow = (MODE == 0) ? lb[rc] : rc;
    Aact += (size_t)arow * Kd + ((tid & 3) << 4);
  }
  int k4 = tid >> 4, ng = tid & 15;

  f32x4 acc[2][2];
  #pragma unroll
  for (int m = 0; m < 2; m++)
    #pragma unroll
    for (int n = 0; n < 2; n++)
      acc[m][n] = (f32x4){0.f, 0.f, 0.f, 0.f};

  uint4 avv[2]; f32x4 bv[4];
  #define LOAD_T(k0) do {                                              \
    _Pragma("unroll")                                                  \
    for (int i = 0; i < 2; i++)                                        \
      avv[i] = *(const uint4*)(Aact + (k0) + i * 8);                   \
    _Pragma("unroll")                                                  \
    for (int r = 0; r < 4; r++)                                        \
      bv[r] = *(const f32x4*)(Wd + (size_t)((k0) + k4 * 4 + r) * H_DIM + nb + ng * 4); \
    } while (0)

  LOAD_T(0);
  const int NT = Kd / 64;
  for (int t = 0; t < NT; t++) {
    __syncthreads();
    #pragma unroll
    for (int i = 0; i < 2; i++)
      *(uint4*)&sA[tid >> 2][((tid & 3) << 4) + i * 8] = avv[i];
    #pragma unroll
    for (int i = 0; i < 4; i++) {
      bf16x4 tv;
      tv[0] = (bf16)bv[0][i]; tv[1] = (bf16)bv[1][i]; tv[2] = (bf16)bv[2][i]; tv[3] = (bf16)bv[3][i];
      *(bf16x4*)&sB[ng * 4 + i][k4 * 4] = tv;
    }
    __syncthreads();
    if (t + 1 < NT) LOAD_T((t + 1) * 64);
    #pragma unroll
    for (int kk = 0; kk < 2; kk++) {
      bf16x8 af[2];
      #pragma unroll
      for (int m = 0; m < 2; m++)
        af[m] = *(const bf16x8*)&sA[wr * 32 + m * 16 + (lane & 15)][kk * 32 + (lane >> 4) * 8];
      #pragma unroll
      for (int n = 0; n < 2; n++) {
        bf16x8 bfv = *(const bf16x8*)&sB[wc * 32 + n * 16 + (lane & 15)][kk * 32 + (lane >> 4) * 8];
        #pragma unroll
        for (int m = 0; m < 2; m++)
          acc[m][n] = __builtin_amdgcn_mfma_f32_16x16x32_bf16(af[m], bfv, acc[m][n], 0, 0, 0);
      }
    }
  }
  #undef LOAD_T
  #pragma unroll
  for (int m = 0; m < 2; m++) {
    #pragma unroll
    for (int q = 0; q < 4; q++) {
      int gr = mt + wr * 32 + m * 16 + (lane >> 4) * 4 + q;
      if (gr < count) {
        #pragma unroll
        for (int n = 0; n < 2; n++) {
          int col = nb + wc * 32 + n * 16 + (lane & 15);
          if (MODE == 0) {
            dstb[(size_t)lb[gr] * H_DIM + col] = (bf16)acc[m][n][q];
          } else if (MODE == 1) {
            dstf[(size_t)gr * H_DIM + col] = sg[gr] * acc[m][n][q];
          } else {
            dstf[(size_t)gr * H_DIM + col] += sg[gr] * acc[m][n][q];
          }
        }
      }
    }
  }
}

// ---------------- combine: out += sum_k topw*dslot ----------------
__global__ __launch_bounds__(256) void combine_kernel(
    const bf16* __restrict__ dslot, const float* __restrict__ topw,
    float* __restrict__ out)
{
  int t = blockIdx.x;
  int h = threadIdx.x * 8;
  float w0 = topw[t * 4 + 0], w1 = topw[t * 4 + 1];
  float w2 = topw[t * 4 + 2], w3 = topw[t * 4 + 3];
  bf16x8 a0 = *(const bf16x8*)&dslot[(size_t)(t * 4 + 0) * H_DIM + h];
  bf16x8 a1 = *(const bf16x8*)&dslot[(size_t)(t * 4 + 1) * H_DIM + h];
  bf16x8 a2 = *(const bf16x8*)&dslot[(size_t)(t * 4 + 2) * H_DIM + h];
  bf16x8 a3 = *(const bf16x8*)&dslot[(size_t)(t * 4 + 3) * H_DIM + h];
  f32x4 o0 = *(f32x4*)&out[(size_t)t * H_DIM + h];
  f32x4 o1 = *(f32x4*)&out[(size_t)t * H_DIM + h + 4];
  float o[8] = {o0[0], o0[1], o0[2], o0[3], o1[0], o1[1], o1[2], o1[3]};
  #pragma unroll
  for (int j = 0; j < 8; j++)
    o[j] += w0 * (float)a0[j] + w1 * (float)a1[j] + w2 * (float)a2[j]
          + w3 * (float)a3[j];
  *(f32x4*)&out[(size_t)t * H_DIM + h]     = (f32x4){o[0], o[1], o[2], o[3]};
  *(f32x4*)&out[(size_t)t * H_DIM + h + 4] = (f32x4){o[4], o[5], o[6], o[7]};
}

extern "C" void kernel_launch(void* const* d_in, const int* in_sizes, int n_in,
                              void* d_out, int out_size, void* d_ws, size_t ws_size,
                              hipStream_t stream) {
  const float* x   = (const float*)d_in[0];
  const float* rw  = (const float*)d_in[1];
  const float* wg  = (const float*)d_in[2];
  const float* wu  = (const float*)d_in[3];
  const float* wd  = (const float*)d_in[4];
  const float* swg = (const float*)d_in[5];
  const float* swu = (const float*)d_in[6];
  const float* swd = (const float*)d_in[7];
  const float* sgw = (const float*)d_in[8];
  float* out = (float*)d_out;
  char* ws = (char*)d_ws;

  // total ws usage: ~26.2 MiB (must stay well under harness ws_size;
  // 34 MiB in round 3 overflowed into an input tensor -> replay divergence)
  size_t off = 0;
  int*   counts = (int*)(ws + off); off += 256;
  int*   lists  = (int*)(ws + off); off += (size_t)N_EXP * T_TOK * 4;           // 128 KB
  float* topw   = (float*)(ws + off); off += (size_t)T_TOK * TOPK * 4;          // 16 KB
  float* sg     = (float*)(ws + off); off += (size_t)T_TOK * 4;                 // 4 KB
  bf16*  act    = (bf16*)(ws + off); off += (size_t)T_TOK * TOPK * F_DIM * 2;   // 6.3 MB
  bf16*  acts   = (bf16*)(ws + off); off += (size_t)T_TOK * FS_HALF * 2;        // 4.2 MB
  bf16*  dslot  = (bf16*)(ws + off); off += (size_t)T_TOK * TOPK * H_DIM * 2;   // 16.8 MB

  hipMemsetAsync(counts, 0, 256, stream);

  router_kernel<<<T_TOK, 256, 0, stream>>>(x, rw, sgw, topw, sg, counts, lists);

  // expert gate/up: act[slot][F]
  gateup_mfma<true><<<dim3(8, F_DIM / 64, N_EXP), 256, 0, stream>>>(
      x, wg, wu, act, lists, counts, F_DIM, F_DIM);
  // shared gate/up half 0: acts[t][0..2047] of FS
  gateup_mfma<false><<<dim3(T_TOK / 64, FS_HALF / 64, 1), 256, 0, stream>>>(
      x, swg, swu, acts, nullptr, nullptr, FS_HALF, FS_DIM);
  // expert down: dslot[slot][H]
  down_mfma<0><<<dim3(8, H_DIM / 64, N_EXP), 256, 0, stream>>>(
      act, wd, dslot, nullptr, nullptr, lists, counts, F_DIM);
  // shared down half 0: out = sg * (acts @ swd[0:2048,:])
  down_mfma<1><<<dim3(T_TOK / 64, H_DIM / 64, 1), 256, 0, stream>>>(
      acts, swd, nullptr, out, sg, nullptr, nullptr, FS_HALF);
  // shared gate/up half 1 (reuses acts; waits for down<1> via stream order)
  gateup_mfma<false><<<dim3(T_TOK / 64, FS_HALF / 64, 1), 256, 0, stream>>>(
      x, swg + FS_HALF, swu + FS_HALF, acts, nullptr, nullptr, FS_HALF, FS_DIM);
  // shared down half 1: out += sg * (acts @ swd[2048:,:])
  down_mfma<2><<<dim3(T_TOK / 64, H_DIM / 64, 1), 256, 0, stream>>>(
      acts, swd + (size_t)FS_HALF * H_DIM, nullptr, out, sg, nullptr, nullptr, FS_HALF);
  // add expert contributions
  combine_kernel<<<T_TOK, 256, 0, stream>>>(dslot, topw, out);
}

// Round 5
// 511.129 us; speedup vs baseline: 6.8459x; 2.0529x over previous
//
#include <hip/hip_runtime.h>
#include <math.h>

#define T_TOK 1024
#define H_DIM 2048
#define N_EXP 32
#define TOPK  4
#define F_DIM 768
#define FS_DIM 4096
#define FS_HALF 2048

typedef __bf16 bf16;
typedef __attribute__((ext_vector_type(2))) __bf16 bf16x2;
typedef __attribute__((ext_vector_type(4))) __bf16 bf16x4;
typedef __attribute__((ext_vector_type(8))) __bf16 bf16x8;
typedef __attribute__((ext_vector_type(4))) float f32x4;

// ---------------- router: fp32 logits -> softmax -> top4 -> lists ----------------
__global__ __launch_bounds__(256) void router_kernel(
    const float* __restrict__ x, const float* __restrict__ rw,
    const float* __restrict__ sgw,
    float* __restrict__ topw, float* __restrict__ sg,
    int* __restrict__ counts, int* __restrict__ lists)
{
  int t = blockIdx.x; int tid = threadIdx.x;
  int lane = tid & 63, wave = tid >> 6;
  float acc[N_EXP];
  #pragma unroll
  for (int e = 0; e < N_EXP; e++) acc[e] = 0.f;
  float accs = 0.f;
  const float* xr = x + (size_t)t * H_DIM;
  for (int h = tid; h < H_DIM; h += 256) {
    float xv = xr[h];
    accs += xv * sgw[h];
    #pragma unroll
    for (int e = 0; e < N_EXP; e++) acc[e] += xv * rw[e * H_DIM + h];
  }
  __shared__ float red[4][N_EXP];
  __shared__ float reds[4];
  __shared__ float logits[N_EXP];
  #pragma unroll
  for (int e = 0; e < N_EXP; e++) {
    float v = acc[e];
    for (int off = 32; off; off >>= 1) v += __shfl_down(v, off, 64);
    if (lane == 0) red[wave][e] = v;
  }
  {
    float v = accs;
    for (int off = 32; off; off >>= 1) v += __shfl_down(v, off, 64);
    if (lane == 0) reds[wave] = v;
  }
  __syncthreads();
  if (tid < N_EXP) logits[tid] = red[0][tid] + red[1][tid] + red[2][tid] + red[3][tid];
  __syncthreads();
  if (tid == 0) {
    float m = -1e30f;
    #pragma unroll
    for (int e = 0; e < N_EXP; e++) m = fmaxf(m, logits[e]);
    float p[N_EXP];
    #pragma unroll
    for (int e = 0; e < N_EXP; e++) p[e] = expf(logits[e] - m);
    int ids[TOPK]; float vs[TOPK]; float wsum = 0.f;
    #pragma unroll
    for (int k = 0; k < TOPK; k++) {
      int best = 0; float bv = -1.f;
      for (int e = 0; e < N_EXP; e++) {
        if (p[e] > bv) { bv = p[e]; best = e; }
      }
      ids[k] = best; vs[k] = bv; wsum += bv; p[best] = -2.f;
    }
    float inv = 1.f / wsum;
    float sgs = reds[0] + reds[1] + reds[2] + reds[3];
    sg[t] = 1.f / (1.f + expf(-sgs));
    #pragma unroll
    for (int k = 0; k < TOPK; k++) {
      int slot = t * TOPK + k;
      topw[slot] = vs[k] * inv;
      int pos = atomicAdd(&counts[ids[k]], 1);
      lists[ids[k] * T_TOK + pos] = slot;
    }
  }
}

// ------- fused gate/up dual GEMM + SwiGLU, 64x64 tile, BK=32, 2-deep pipeline -------
// block id < n_shared: shared expert (rows = tokens, W = sw* + col_off, ldb=FS)
// block id >= n_shared: expert path (rows gathered via lists, W = w*[e])
__global__ __launch_bounds__(256, 4) void gateup_fused(
    const float* __restrict__ X,
    const float* __restrict__ wg_, const float* __restrict__ wu_,
    const float* __restrict__ swg, const float* __restrict__ swu,
    bf16* __restrict__ act, bf16* __restrict__ acts,
    const int* __restrict__ lists, const int* __restrict__ counts,
    int n_shared, int col_off)
{
  int id = blockIdx.x;
  bool gather = id >= n_shared;
  const float *Wg, *Wu; const int* lb = nullptr;
  int count, mt, fb, ldb, Nout; bf16* C;
  if (gather) {
    int r = id - n_shared;
    int e = r / 96; int rr = r - e * 96;
    fb = (rr % 12) * 64; mt = (rr / 12) * 64;
    count = counts[e]; lb = lists + e * T_TOK;
    Wg = wg_ + (size_t)e * H_DIM * F_DIM;
    Wu = wu_ + (size_t)e * H_DIM * F_DIM;
    ldb = F_DIM; Nout = F_DIM; C = act;
  } else {
    fb = (id & 31) * 64; mt = (id >> 5) * 64;
    count = T_TOK; ldb = FS_DIM; Nout = FS_HALF;
    Wg = swg + col_off; Wu = swu + col_off;
    C = acts;
  }
  if (mt >= count) return;

  int tid = threadIdx.x;
  int lane = tid & 63, wid = tid >> 6;
  int wr = wid >> 1, wc = wid & 1;   // wave tile: 32 rows x 32 cols

  __shared__ alignas(16) bf16 sA [64][40];
  __shared__ alignas(16) bf16 sBg[64][40];   // [n][k] transposed
  __shared__ alignas(16) bf16 sBu[64][40];

  const float* aptr;
  {
    int r = mt + (tid >> 2);
    int rc = r < count ? r : count - 1;
    int tok = gather ? (lb[rc] >> 2) : rc;
    aptr = X + (size_t)tok * H_DIM + ((tid & 3) << 3);
  }
  int tid7 = tid & 127;
  int bk4 = (tid7 >> 4) << 2;   // 0,4,...,28
  int bng = tid7 & 15;
  const float* bptr = (tid < 128 ? Wg : Wu) + (size_t)bk4 * ldb + fb + bng * 4;
  bf16* bdst = (tid < 128) ? &sBg[0][0] : &sBu[0][0];

  f32x4 accg[2][2], accu[2][2];
  #pragma unroll
  for (int m = 0; m < 2; m++)
    #pragma unroll
    for (int n = 0; n < 2; n++) {
      accg[m][n] = (f32x4){0.f,0.f,0.f,0.f};
      accu[m][n] = (f32x4){0.f,0.f,0.f,0.f};
    }

  f32x4 avA[2], bvA[4], avB[2], bvB[4];

  #define ISSUE(av, bv, k0) do {                                      \
    av[0] = *(const f32x4*)(aptr + (k0));                             \
    av[1] = *(const f32x4*)(aptr + (k0) + 4);                         \
    _Pragma("unroll")                                                 \
    for (int r_ = 0; r_ < 4; r_++)                                    \
      bv[r_] = *(const f32x4*)(bptr + (size_t)((k0) + r_) * ldb);     \
  } while (0)

  #define STAGE(av, bv) do {                                          \
    bf16x8 t8;                                                        \
    _Pragma("unroll")                                                 \
    for (int j_ = 0; j_ < 4; j_++) {                                  \
      t8[j_] = (bf16)av[0][j_]; t8[4 + j_] = (bf16)av[1][j_];         \
    }                                                                 \
    *(bf16x8*)&sA[tid >> 2][(tid & 3) << 3] = t8;                     \
    _Pragma("unroll")                                                 \
    for (int i_ = 0; i_ < 4; i_++) {                                  \
      bf16x4 tb;                                                      \
      tb[0] = (bf16)bv[0][i_]; tb[1] = (bf16)bv[1][i_];               \
      tb[2] = (bf16)bv[2][i_]; tb[3] = (bf16)bv[3][i_];               \
      *(bf16x4*)(bdst + (bng * 4 + i_) * 40 + bk4) = tb;              \
    }                                                                 \
  } while (0)

  #define MFMA_PHASE() do {                                           \
    int fc = (lane >> 4) << 3;                                        \
    bf16x8 af0 = *(const bf16x8*)&sA[wr * 32 + (lane & 15)][fc];      \
    bf16x8 af1 = *(const bf16x8*)&sA[wr * 32 + 16 + (lane & 15)][fc]; \
    _Pragma("unroll")                                                 \
    for (int n_ = 0; n_ < 2; n_++) {                                  \
      int nr = wc * 32 + n_ * 16 + (lane & 15);                       \
      bf16x8 bg = *(const bf16x8*)&sBg[nr][fc];                       \
      bf16x8 bu = *(const bf16x8*)&sBu[nr][fc];                       \
      accg[0][n_] = __builtin_amdgcn_mfma_f32_16x16x32_bf16(af0, bg, accg[0][n_], 0,0,0); \
      accu[0][n_] = __builtin_amdgcn_mfma_f32_16x16x32_bf16(af0, bu, accu[0][n_], 0,0,0); \
      accg[1][n_] = __builtin_amdgcn_mfma_f32_16x16x32_bf16(af1, bg, accg[1][n_], 0,0,0); \
      accu[1][n_] = __builtin_amdgcn_mfma_f32_16x16x32_bf16(af1, bu, accu[1][n_], 0,0,0); \
    }                                                                 \
  } while (0)

  ISSUE(avA, bvA, 0);
  ISSUE(avB, bvB, 32);
  const int NT = H_DIM / 32;   // 64
  for (int t = 0; t < NT; t += 2) {
    __syncthreads();
    STAGE(avA, bvA);
    __syncthreads();
    if (t + 2 < NT) ISSUE(avA, bvA, (t + 2) * 32);
    MFMA_PHASE();
    __syncthreads();
    STAGE(avB, bvB);
    __syncthreads();
    if (t + 3 < NT) ISSUE(avB, bvB, (t + 3) * 32);
    MFMA_PHASE();
  }
  #undef ISSUE
  #undef STAGE
  #undef MFMA_PHASE

  #pragma unroll
  for (int m = 0; m < 2; m++) {
    #pragma unroll
    for (int q = 0; q < 4; q++) {
      int gr = mt + wr * 32 + m * 16 + (lane >> 4) * 4 + q;
      if (gr < count) {
        size_t rowo = (gather ? (size_t)lb[gr] : (size_t)gr) * Nout;
        #pragma unroll
        for (int n = 0; n < 2; n++) {
          float g = accg[m][n][q], u = accu[m][n][q];
          C[rowo + fb + wc * 32 + n * 16 + (lane & 15)] =
              (bf16)(g / (1.f + __expf(-g)) * u);
        }
      }
    }
  }
}

// ------- fused down-proj, 64x64 tile, BK=32, 2-deep pipeline -------
// id < n_shared: shared (A=acts, W=swd+row_off, out = / += sg*acc)
// id >= n_shared: expert (A=act gathered, W=wd[e], dslot[slot] = bf16 acc)
__global__ __launch_bounds__(256, 4) void down_fused(
    const bf16* __restrict__ act, const bf16* __restrict__ acts,
    const float* __restrict__ wd_, const float* __restrict__ swd,
    bf16* __restrict__ dslot, float* __restrict__ out,
    const float* __restrict__ sg,
    const int* __restrict__ lists, const int* __restrict__ counts,
    int n_shared, int row_off)
{
  int id = blockIdx.x;
  bool expert = id >= n_shared;
  const bf16* A; const float* W; const int* lb = nullptr;
  int count, mt, nb, Kd, lda;
  if (expert) {
    int r = id - n_shared;
    int e = r >> 8; int rr = r & 255;
    nb = (rr & 31) * 64; mt = ((rr >> 5) & 7) * 64;
    count = counts[e]; lb = lists + e * T_TOK;
    A = act; lda = F_DIM; Kd = F_DIM;
    W = wd_ + (size_t)e * F_DIM * H_DIM;
  } else {
    nb = (id & 31) * 64; mt = (id >> 5) * 64;
    count = T_TOK; A = acts; lda = FS_HALF; Kd = FS_HALF;
    W = swd + (size_t)row_off * H_DIM;
  }
  if (mt >= count) return;

  int tid = threadIdx.x;
  int lane = tid & 63, wid = tid >> 6;
  int wr = wid >> 1, wc = wid & 1;

  __shared__ alignas(16) bf16 sA[64][40];
  __shared__ alignas(16) bf16 sB[64][40];

  const bf16* aptr;
  {
    int r = mt + (tid >> 2);
    int rc = r < count ? r : count - 1;
    int ar = expert ? lb[rc] : rc;
    aptr = A + (size_t)ar * lda + ((tid & 3) << 3);
  }
  int bk2 = (tid >> 4) << 1;    // 0,2,...,30
  int bng = tid & 15;
  const float* bptr = W + (size_t)bk2 * H_DIM + nb + bng * 4;

  f32x4 acc[2][2];
  #pragma unroll
  for (int m = 0; m < 2; m++)
    #pragma unroll
    for (int n = 0; n < 2; n++)
      acc[m][n] = (f32x4){0.f,0.f,0.f,0.f};

  uint4 avA, avB; f32x4 bvA[2], bvB[2];

  #define ISSUE(av, bv, k0) do {                                      \
    av = *(const uint4*)(aptr + (k0));                                \
    bv[0] = *(const f32x4*)(bptr + (size_t)(k0) * H_DIM);             \
    bv[1] = *(const f32x4*)(bptr + (size_t)((k0) + 1) * H_DIM);       \
  } while (0)

  #define STAGE(av, bv) do {                                          \
    *(uint4*)&sA[tid >> 2][(tid & 3) << 3] = av;                      \
    _Pragma("unroll")                                                 \
    for (int i_ = 0; i_ < 4; i_++) {                                  \
      bf16x2 tb;                                                      \
      tb[0] = (bf16)bv[0][i_]; tb[1] = (bf16)bv[1][i_];               \
      *(bf16x2*)&sB[bng * 4 + i_][bk2] = tb;                          \
    }                                                                 \
  } while (0)

  #define MFMA_PHASE() do {                                           \
    int fc = (lane >> 4) << 3;                                        \
    bf16x8 af0 = *(const bf16x8*)&sA[wr * 32 + (lane & 15)][fc];      \
    bf16x8 af1 = *(const bf16x8*)&sA[wr * 32 + 16 + (lane & 15)][fc]; \
    _Pragma("unroll")                                                 \
    for (int n_ = 0; n_ < 2; n_++) {                                  \
      bf16x8 bb = *(const bf16x8*)&sB[wc * 32 + n_ * 16 + (lane & 15)][fc]; \
      acc[0][n_] = __builtin_amdgcn_mfma_f32_16x16x32_bf16(af0, bb, acc[0][n_], 0,0,0); \
      acc[1][n_] = __builtin_amdgcn_mfma_f32_16x16x32_bf16(af1, bb, acc[1][n_], 0,0,0); \
    }                                                                 \
  } while (0)

  ISSUE(avA, bvA, 0);
  ISSUE(avB, bvB, 32);
  const int NT = Kd / 32;   // 24 or 64 (even)
  for (int t = 0; t < NT; t += 2) {
    __syncthreads();
    STAGE(avA, bvA);
    __syncthreads();
    if (t + 2 < NT) ISSUE(avA, bvA, (t + 2) * 32);
    MFMA_PHASE();
    __syncthreads();
    STAGE(avB, bvB);
    __syncthreads();
    if (t + 3 < NT) ISSUE(avB, bvB, (t + 3) * 32);
    MFMA_PHASE();
  }
  #undef ISSUE
  #undef STAGE
  #undef MFMA_PHASE

  #pragma unroll
  for (int m = 0; m < 2; m++) {
    #pragma unroll
    for (int q = 0; q < 4; q++) {
      int gr = mt + wr * 32 + m * 16 + (lane >> 4) * 4 + q;
      if (gr < count) {
        #pragma unroll
        for (int n = 0; n < 2; n++) {
          int col = nb + wc * 32 + n * 16 + (lane & 15);
          if (expert) {
            dslot[(size_t)lb[gr] * H_DIM + col] = (bf16)acc[m][n][q];
          } else if (row_off == 0) {
            out[(size_t)gr * H_DIM + col] = sg[gr] * acc[m][n][q];
          } else {
            out[(size_t)gr * H_DIM + col] += sg[gr] * acc[m][n][q];
          }
        }
      }
    }
  }
}

// ---------------- combine: out += sum_k topw*dslot ----------------
__global__ __launch_bounds__(256) void combine_kernel(
    const bf16* __restrict__ dslot, const float* __restrict__ topw,
    float* __restrict__ out)
{
  int t = blockIdx.x;
  int h = threadIdx.x * 8;
  float w0 = topw[t * 4 + 0], w1 = topw[t * 4 + 1];
  float w2 = topw[t * 4 + 2], w3 = topw[t * 4 + 3];
  bf16x8 a0 = *(const bf16x8*)&dslot[(size_t)(t * 4 + 0) * H_DIM + h];
  bf16x8 a1 = *(const bf16x8*)&dslot[(size_t)(t * 4 + 1) * H_DIM + h];
  bf16x8 a2 = *(const bf16x8*)&dslot[(size_t)(t * 4 + 2) * H_DIM + h];
  bf16x8 a3 = *(const bf16x8*)&dslot[(size_t)(t * 4 + 3) * H_DIM + h];
  f32x4 o0 = *(f32x4*)&out[(size_t)t * H_DIM + h];
  f32x4 o1 = *(f32x4*)&out[(size_t)t * H_DIM + h + 4];
  float o[8] = {o0[0], o0[1], o0[2], o0[3], o1[0], o1[1], o1[2], o1[3]};
  #pragma unroll
  for (int j = 0; j < 8; j++)
    o[j] += w0 * (float)a0[j] + w1 * (float)a1[j] + w2 * (float)a2[j]
          + w3 * (float)a3[j];
  *(f32x4*)&out[(size_t)t * H_DIM + h]     = (f32x4){o[0], o[1], o[2], o[3]};
  *(f32x4*)&out[(size_t)t * H_DIM + h + 4] = (f32x4){o[4], o[5], o[6], o[7]};
}

extern "C" void kernel_launch(void* const* d_in, const int* in_sizes, int n_in,
                              void* d_out, int out_size, void* d_ws, size_t ws_size,
                              hipStream_t stream) {
  const float* x   = (const float*)d_in[0];
  const float* rw  = (const float*)d_in[1];
  const float* wg  = (const float*)d_in[2];
  const float* wu  = (const float*)d_in[3];
  const float* wd  = (const float*)d_in[4];
  const float* swg = (const float*)d_in[5];
  const float* swu = (const float*)d_in[6];
  const float* swd = (const float*)d_in[7];
  const float* sgw = (const float*)d_in[8];
  float* out = (float*)d_out;
  char* ws = (char*)d_ws;

  // ws total ~26.2 MiB (34 MiB overflowed in round 3 -> replay divergence)
  size_t off = 0;
  int*   counts = (int*)(ws + off); off += 256;
  int*   lists  = (int*)(ws + off); off += (size_t)N_EXP * T_TOK * 4;           // 128 KB
  float* topw   = (float*)(ws + off); off += (size_t)T_TOK * TOPK * 4;          // 16 KB
  float* sg     = (float*)(ws + off); off += (size_t)T_TOK * 4;                 // 4 KB
  bf16*  act    = (bf16*)(ws + off); off += (size_t)T_TOK * TOPK * F_DIM * 2;   // 6.3 MB
  bf16*  acts   = (bf16*)(ws + off); off += (size_t)T_TOK * FS_HALF * 2;        // 4.2 MB
  bf16*  dslot  = (bf16*)(ws + off); off += (size_t)T_TOK * TOPK * H_DIM * 2;   // 16.8 MB

  hipMemsetAsync(counts, 0, 256, stream);

  router_kernel<<<T_TOK, 256, 0, stream>>>(x, rw, sgw, topw, sg, counts, lists);

  // P1: shared gate/up half0 (512 blocks, first) + expert gate/up (3072 blocks)
  gateup_fused<<<512 + 3072, 256, 0, stream>>>(
      x, wg, wu, swg, swu, act, acts, lists, counts, 512, 0);
  // P2: shared down half0 (512, writes out=) + expert down (8192, writes dslot)
  down_fused<<<512 + 8192, 256, 0, stream>>>(
      act, acts, wd, swd, dslot, out, sg, lists, counts, 512, 0);
  // P3: shared gate/up half1 (reuses acts)
  gateup_fused<<<512, 256, 0, stream>>>(
      x, wg, wu, swg, swu, act, acts, lists, counts, 512, FS_HALF);
  // P4: shared down half1 (out +=)
  down_fused<<<512, 256, 0, stream>>>(
      act, acts, wd, swd, dslot, out, sg, lists, counts, 512, FS_HALF);
  // P5: add expert contributions
  combine_kernel<<<T_TOK, 256, 0, stream>>>(dslot, topw, out);
}

// Round 6
// 420.161 us; speedup vs baseline: 8.3281x; 1.2165x over previous
//
#include <hip/hip_runtime.h>
#include <math.h>

#define T_TOK 1024
#define H_DIM 2048
#define N_EXP 32
#define TOPK  4
#define F_DIM 768
#define FS_DIM 4096
#define FS_HALF 2048

typedef __bf16 bf16;
typedef __attribute__((ext_vector_type(2))) __bf16 bf16x2;
typedef __attribute__((ext_vector_type(4))) __bf16 bf16x4;
typedef __attribute__((ext_vector_type(8))) __bf16 bf16x8;
typedef __attribute__((ext_vector_type(4))) float f32x4;

// raw barrier: drain my ds_writes (lgkm) but let global prefetch loads
// (vmcnt) stay in flight across the barrier (AITER pattern). "memory"
// clobber = compiler fence so ds ops can't cross; sched_barrier(0) pins.
#define BAR() do {                                        \
    asm volatile("s_waitcnt lgkmcnt(0)" ::: "memory");    \
    __builtin_amdgcn_s_barrier();                         \
    __builtin_amdgcn_sched_barrier(0);                    \
  } while (0)

// ---------------- router: fp32 logits -> softmax -> top4 -> lists ----------------
__global__ __launch_bounds__(256) void router_kernel(
    const float* __restrict__ x, const float* __restrict__ rw,
    const float* __restrict__ sgw,
    float* __restrict__ topw, float* __restrict__ sg,
    int* __restrict__ counts, int* __restrict__ lists)
{
  int t = blockIdx.x; int tid = threadIdx.x;
  int lane = tid & 63, wave = tid >> 6;
  float acc[N_EXP];
  #pragma unroll
  for (int e = 0; e < N_EXP; e++) acc[e] = 0.f;
  float accs = 0.f;
  const float* xr = x + (size_t)t * H_DIM;
  for (int h = tid; h < H_DIM; h += 256) {
    float xv = xr[h];
    accs += xv * sgw[h];
    #pragma unroll
    for (int e = 0; e < N_EXP; e++) acc[e] += xv * rw[e * H_DIM + h];
  }
  __shared__ float red[4][N_EXP];
  __shared__ float reds[4];
  __shared__ float logits[N_EXP];
  #pragma unroll
  for (int e = 0; e < N_EXP; e++) {
    float v = acc[e];
    for (int off = 32; off; off >>= 1) v += __shfl_down(v, off, 64);
    if (lane == 0) red[wave][e] = v;
  }
  {
    float v = accs;
    for (int off = 32; off; off >>= 1) v += __shfl_down(v, off, 64);
    if (lane == 0) reds[wave] = v;
  }
  __syncthreads();
  if (tid < N_EXP) logits[tid] = red[0][tid] + red[1][tid] + red[2][tid] + red[3][tid];
  __syncthreads();
  if (tid == 0) {
    float m = -1e30f;
    #pragma unroll
    for (int e = 0; e < N_EXP; e++) m = fmaxf(m, logits[e]);
    float p[N_EXP];
    #pragma unroll
    for (int e = 0; e < N_EXP; e++) p[e] = expf(logits[e] - m);
    int ids[TOPK]; float vs[TOPK]; float wsum = 0.f;
    #pragma unroll
    for (int k = 0; k < TOPK; k++) {
      int best = 0; float bv = -1.f;
      for (int e = 0; e < N_EXP; e++) {
        if (p[e] > bv) { bv = p[e]; best = e; }
      }
      ids[k] = best; vs[k] = bv; wsum += bv; p[best] = -2.f;
    }
    float inv = 1.f / wsum;
    float sgs = reds[0] + reds[1] + reds[2] + reds[3];
    sg[t] = 1.f / (1.f + expf(-sgs));
    #pragma unroll
    for (int k = 0; k < TOPK; k++) {
      int slot = t * TOPK + k;
      topw[slot] = vs[k] * inv;
      int pos = atomicAdd(&counts[ids[k]], 1);
      lists[ids[k] * T_TOK + pos] = slot;
    }
  }
}

// ------- fused gate/up dual GEMM + SwiGLU, 64x64 tile, BK=32 -------
// LDS double-buffer, ONE raw barrier per K-step, 2-deep reg prefetch.
// id <  n_shared : shared expert rows=tokens, W=sw*+col_off (ldb=FS_DIM)
// id >= n_shared : expert path, XCD-clustered (id%8 == e%8), W=w*[e]
__global__ __launch_bounds__(256, 4) void gateup_fused(
    const float* __restrict__ X,
    const float* __restrict__ wg_, const float* __restrict__ wu_,
    const float* __restrict__ swg, const float* __restrict__ swu,
    bf16* __restrict__ act, bf16* __restrict__ acts,
    const int* __restrict__ lists, const int* __restrict__ counts,
    int n_shared, int sh_fbs, int actsN, int col_off)
{
  int id = blockIdx.x;
  bool gather = id >= n_shared;
  const float *Wg, *Wu; const int* lb = nullptr;
  int count, mt, fb, ldb, Nout; bf16* C;
  if (gather) {
    int g = id - n_shared;
    int j = g >> 3;
    int e = (g & 7) + 8 * (j / 96);     // all 96 blocks of expert e share an XCD
    int rr = j % 96;
    fb = (rr % 12) * 64; mt = (rr / 12) * 64;
    count = counts[e]; lb = lists + e * T_TOK;
    Wg = wg_ + (size_t)e * H_DIM * F_DIM;
    Wu = wu_ + (size_t)e * H_DIM * F_DIM;
    ldb = F_DIM; Nout = F_DIM; C = act;
  } else {
    fb = (id % sh_fbs) * 64; mt = (id / sh_fbs) * 64;
    count = T_TOK; ldb = FS_DIM; Nout = actsN;
    Wg = swg + col_off; Wu = swu + col_off;
    C = acts;
  }
  if (mt >= count) return;

  int tid = threadIdx.x;
  int lane = tid & 63, wid = tid >> 6;
  int wr = wid >> 1, wc = wid & 1;   // wave tile: 32 rows x 32 cols

  __shared__ alignas(16) bf16 sA [2][64][40];
  __shared__ alignas(16) bf16 sBg[2][64][40];   // [n][k] transposed
  __shared__ alignas(16) bf16 sBu[2][64][40];

  const float* aptr;
  {
    int r = mt + (tid >> 2);
    int rc = r < count ? r : count - 1;
    int tok = gather ? (lb[rc] >> 2) : rc;
    aptr = X + (size_t)tok * H_DIM + ((tid & 3) << 3);
  }
  int tid7 = tid & 127;
  int bk4 = (tid7 >> 4) << 2;   // 0,4,...,28
  int bng = tid7 & 15;
  const float* bptr = (tid < 128 ? Wg : Wu) + (size_t)bk4 * ldb + fb + bng * 4;

  f32x4 accg[2][2], accu[2][2];
  #pragma unroll
  for (int m = 0; m < 2; m++)
    #pragma unroll
    for (int n = 0; n < 2; n++) {
      accg[m][n] = (f32x4){0.f,0.f,0.f,0.f};
      accu[m][n] = (f32x4){0.f,0.f,0.f,0.f};
    }

  f32x4 avA[2], bvA[4], avB[2], bvB[4];

  #define ISSUE(av, bv, k0) do {                                      \
    av[0] = *(const f32x4*)(aptr + (k0));                             \
    av[1] = *(const f32x4*)(aptr + (k0) + 4);                         \
    _Pragma("unroll")                                                 \
    for (int r_ = 0; r_ < 4; r_++)                                    \
      bv[r_] = *(const f32x4*)(bptr + (size_t)((k0) + r_) * ldb);     \
  } while (0)

  #define STAGE(b, av, bv) do {                                       \
    bf16x8 t8;                                                        \
    _Pragma("unroll")                                                 \
    for (int j_ = 0; j_ < 4; j_++) {                                  \
      t8[j_] = (bf16)av[0][j_]; t8[4 + j_] = (bf16)av[1][j_];         \
    }                                                                 \
    *(bf16x8*)&sA[b][tid >> 2][(tid & 3) << 3] = t8;                  \
    bf16* bdst_ = (tid < 128) ? &sBg[b][0][0] : &sBu[b][0][0];        \
    _Pragma("unroll")                                                 \
    for (int i_ = 0; i_ < 4; i_++) {                                  \
      bf16x4 tb;                                                      \
      tb[0] = (bf16)bv[0][i_]; tb[1] = (bf16)bv[1][i_];               \
      tb[2] = (bf16)bv[2][i_]; tb[3] = (bf16)bv[3][i_];               \
      *(bf16x4*)(bdst_ + (bng * 4 + i_) * 40 + bk4) = tb;             \
    }                                                                 \
  } while (0)

  #define MFMA_PHASE(b) do {                                          \
    int fc = (lane >> 4) << 3;                                        \
    bf16x8 af0 = *(const bf16x8*)&sA[b][wr * 32 + (lane & 15)][fc];   \
    bf16x8 af1 = *(const bf16x8*)&sA[b][wr * 32 + 16 + (lane & 15)][fc]; \
    _Pragma("unroll")                                                 \
    for (int n_ = 0; n_ < 2; n_++) {                                  \
      int nr = wc * 32 + n_ * 16 + (lane & 15);                       \
      bf16x8 bg = *(const bf16x8*)&sBg[b][nr][fc];                    \
      bf16x8 bu = *(const bf16x8*)&sBu[b][nr][fc];                    \
      accg[0][n_] = __builtin_amdgcn_mfma_f32_16x16x32_bf16(af0, bg, accg[0][n_], 0,0,0); \
      accu[0][n_] = __builtin_amdgcn_mfma_f32_16x16x32_bf16(af0, bu, accu[0][n_], 0,0,0); \
      accg[1][n_] = __builtin_amdgcn_mfma_f32_16x16x32_bf16(af1, bg, accg[1][n_], 0,0,0); \
      accu[1][n_] = __builtin_amdgcn_mfma_f32_16x16x32_bf16(af1, bu, accu[1][n_], 0,0,0); \
    }                                                                 \
  } while (0)

  ISSUE(avA, bvA, 0);
  ISSUE(avB, bvB, 32);
  STAGE(0, avA, bvA);
  BAR();
  const int NT = H_DIM / 32;   // 64
  for (int t = 0; t < NT; t += 2) {
    if (t + 2 < NT) ISSUE(avA, bvA, (t + 2) * 32);
    MFMA_PHASE(0);
    STAGE(1, avB, bvB);
    BAR();
    if (t + 3 < NT) ISSUE(avB, bvB, (t + 3) * 32);
    MFMA_PHASE(1);
    if (t + 2 < NT) STAGE(0, avA, bvA);
    BAR();
  }
  #undef ISSUE
  #undef STAGE
  #undef MFMA_PHASE

  #pragma unroll
  for (int m = 0; m < 2; m++) {
    #pragma unroll
    for (int q = 0; q < 4; q++) {
      int gr = mt + wr * 32 + m * 16 + (lane >> 4) * 4 + q;
      if (gr < count) {
        size_t rowo = (gather ? (size_t)lb[gr] : (size_t)gr) * Nout;
        #pragma unroll
        for (int n = 0; n < 2; n++) {
          float g = accg[m][n][q], u = accu[m][n][q];
          C[rowo + fb + wc * 32 + n * 16 + (lane & 15)] =
              (bf16)(g / (1.f + __expf(-g)) * u);
        }
      }
    }
  }
}

// ------- fused down-proj, 64x64 tile, BK=32, dbuf LDS + raw barriers -------
// id <  n_shared : shared (A=acts [T][lda_sh], K=kd_sh, W=swd+swd_off rows)
// id >= n_shared : expert (A=act gathered, W=wd[e], XCD-clustered)
__global__ __launch_bounds__(256, 4) void down_fused(
    const bf16* __restrict__ act, const bf16* __restrict__ acts,
    const float* __restrict__ wd_, const float* __restrict__ swd,
    bf16* __restrict__ dslot, float* __restrict__ out,
    const float* __restrict__ sg,
    const int* __restrict__ lists, const int* __restrict__ counts,
    int n_shared, int lda_sh, int kd_sh, int swd_off, int accum)
{
  int id = blockIdx.x;
  bool expert = id >= n_shared;
  const bf16* A; const float* W; const int* lb = nullptr;
  int count, mt, nb, Kd, lda;
  if (expert) {
    int g = id - n_shared;
    int j = g >> 3;
    int e = (g & 7) + 8 * (j >> 8);    // cluster expert e's 256 blocks on one XCD
    int rr = j & 255;
    nb = (rr & 31) * 64; mt = (rr >> 5) * 64;
    count = counts[e]; lb = lists + e * T_TOK;
    A = act; lda = F_DIM; Kd = F_DIM;
    W = wd_ + (size_t)e * F_DIM * H_DIM;
  } else {
    nb = (id & 31) * 64; mt = (id >> 5) * 64;
    count = T_TOK; A = acts; lda = lda_sh; Kd = kd_sh;
    W = swd + (size_t)swd_off * H_DIM;
  }
  if (mt >= count) return;

  int tid = threadIdx.x;
  int lane = tid & 63, wid = tid >> 6;
  int wr = wid >> 1, wc = wid & 1;

  __shared__ alignas(16) bf16 sA[2][64][40];
  __shared__ alignas(16) bf16 sB[2][64][40];

  const bf16* aptr;
  {
    int r = mt + (tid >> 2);
    int rc = r < count ? r : count - 1;
    int ar = expert ? lb[rc] : rc;
    aptr = A + (size_t)ar * lda + ((tid & 3) << 3);
  }
  int bk2 = (tid >> 4) << 1;    // 0,2,...,30
  int bng = tid & 15;
  const float* bptr = W + (size_t)bk2 * H_DIM + nb + bng * 4;

  f32x4 acc[2][2];
  #pragma unroll
  for (int m = 0; m < 2; m++)
    #pragma unroll
    for (int n = 0; n < 2; n++)
      acc[m][n] = (f32x4){0.f,0.f,0.f,0.f};

  uint4 avA, avB; f32x4 bvA[2], bvB[2];

  #define ISSUE(av, bv, k0) do {                                      \
    av = *(const uint4*)(aptr + (k0));                                \
    bv[0] = *(const f32x4*)(bptr + (size_t)(k0) * H_DIM);             \
    bv[1] = *(const f32x4*)(bptr + (size_t)((k0) + 1) * H_DIM);      \
  } while (0)

  #define STAGE(b, av, bv) do {                                       \
    *(uint4*)&sA[b][tid >> 2][(tid & 3) << 3] = av;                   \
    _Pragma("unroll")                                                 \
    for (int i_ = 0; i_ < 4; i_++) {                                  \
      bf16x2 tb;                                                      \
      tb[0] = (bf16)bv[0][i_]; tb[1] = (bf16)bv[1][i_];               \
      *(bf16x2*)&sB[b][bng * 4 + i_][bk2] = tb;                       \
    }                                                                 \
  } while (0)

  #define MFMA_PHASE(b) do {                                          \
    int fc = (lane >> 4) << 3;                                        \
    bf16x8 af0 = *(const bf16x8*)&sA[b][wr * 32 + (lane & 15)][fc];   \
    bf16x8 af1 = *(const bf16x8*)&sA[b][wr * 32 + 16 + (lane & 15)][fc]; \
    _Pragma("unroll")                                                 \
    for (int n_ = 0; n_ < 2; n_++) {                                  \
      bf16x8 bb = *(const bf16x8*)&sB[b][wc * 32 + n_ * 16 + (lane & 15)][fc]; \
      acc[0][n_] = __builtin_amdgcn_mfma_f32_16x16x32_bf16(af0, bb, acc[0][n_], 0,0,0); \
      acc[1][n_] = __builtin_amdgcn_mfma_f32_16x16x32_bf16(af1, bb, acc[1][n_], 0,0,0); \
    }                                                                 \
  } while (0)

  ISSUE(avA, bvA, 0);
  ISSUE(avB, bvB, 32);
  STAGE(0, avA, bvA);
  BAR();
  const int NT = Kd / 32;   // 24, 64 or 128 (even)
  for (int t = 0; t < NT; t += 2) {
    if (t + 2 < NT) ISSUE(avA, bvA, (t + 2) * 32);
    MFMA_PHASE(0);
    STAGE(1, avB, bvB);
    BAR();
    if (t + 3 < NT) ISSUE(avB, bvB, (t + 3) * 32);
    MFMA_PHASE(1);
    if (t + 2 < NT) STAGE(0, avA, bvA);
    BAR();
  }
  #undef ISSUE
  #undef STAGE
  #undef MFMA_PHASE

  #pragma unroll
  for (int m = 0; m < 2; m++) {
    #pragma unroll
    for (int q = 0; q < 4; q++) {
      int gr = mt + wr * 32 + m * 16 + (lane >> 4) * 4 + q;
      if (gr < count) {
        #pragma unroll
        for (int n = 0; n < 2; n++) {
          int col = nb + wc * 32 + n * 16 + (lane & 15);
          if (expert) {
            dslot[(size_t)lb[gr] * H_DIM + col] = (bf16)acc[m][n][q];
          } else if (!accum) {
            out[(size_t)gr * H_DIM + col] = sg[gr] * acc[m][n][q];
          } else {
            out[(size_t)gr * H_DIM + col] += sg[gr] * acc[m][n][q];
          }
        }
      }
    }
  }
}

// ---------------- combine: out += sum_k topw*dslot ----------------
__global__ __launch_bounds__(256) void combine_kernel(
    const bf16* __restrict__ dslot, const float* __restrict__ topw,
    float* __restrict__ out)
{
  int t = blockIdx.x;
  int h = threadIdx.x * 8;
  float w0 = topw[t * 4 + 0], w1 = topw[t * 4 + 1];
  float w2 = topw[t * 4 + 2], w3 = topw[t * 4 + 3];
  bf16x8 a0 = *(const bf16x8*)&dslot[(size_t)(t * 4 + 0) * H_DIM + h];
  bf16x8 a1 = *(const bf16x8*)&dslot[(size_t)(t * 4 + 1) * H_DIM + h];
  bf16x8 a2 = *(const bf16x8*)&dslot[(size_t)(t * 4 + 2) * H_DIM + h];
  bf16x8 a3 = *(const bf16x8*)&dslot[(size_t)(t * 4 + 3) * H_DIM + h];
  f32x4 o0 = *(f32x4*)&out[(size_t)t * H_DIM + h];
  f32x4 o1 = *(f32x4*)&out[(size_t)t * H_DIM + h + 4];
  float o[8] = {o0[0], o0[1], o0[2], o0[3], o1[0], o1[1], o1[2], o1[3]};
  #pragma unroll
  for (int j = 0; j < 8; j++)
    o[j] += w0 * (float)a0[j] + w1 * (float)a1[j] + w2 * (float)a2[j]
          + w3 * (float)a3[j];
  *(f32x4*)&out[(size_t)t * H_DIM + h]     = (f32x4){o[0], o[1], o[2], o[3]};
  *(f32x4*)&out[(size_t)t * H_DIM + h + 4] = (f32x4){o[4], o[5], o[6], o[7]};
}

extern "C" void kernel_launch(void* const* d_in, const int* in_sizes, int n_in,
                              void* d_out, int out_size, void* d_ws, size_t ws_size,
                              hipStream_t stream) {
  const float* x   = (const float*)d_in[0];
  const float* rw  = (const float*)d_in[1];
  const float* wg  = (const float*)d_in[2];
  const float* wu  = (const float*)d_in[3];
  const float* wd  = (const float*)d_in[4];
  const float* swg = (const float*)d_in[5];
  const float* swu = (const float*)d_in[6];
  const float* swd = (const float*)d_in[7];
  const float* sgw = (const float*)d_in[8];
  float* out = (float*)d_out;
  char* ws = (char*)d_ws;

  // full-FS path needs 31.61 MB of ws; halves path needs 27.4 MB.
  // (34 MB overflowed in round 3 -> replay divergence; gate at runtime)
  bool fullfs = ws_size >= (size_t)31700000;
  size_t actsN = fullfs ? FS_DIM : FS_HALF;

  size_t off = 0;
  int*   counts = (int*)(ws + off); off += 256;
  int*   lists  = (int*)(ws + off); off += (size_t)N_EXP * T_TOK * 4;           // 128 KB
  float* topw   = (float*)(ws + off); off += (size_t)T_TOK * TOPK * 4;          // 16 KB
  float* sg     = (float*)(ws + off); off += (size_t)T_TOK * 4;                 // 4 KB
  bf16*  act    = (bf16*)(ws + off); off += (size_t)T_TOK * TOPK * F_DIM * 2;   // 6.3 MB
  bf16*  acts   = (bf16*)(ws + off); off += (size_t)T_TOK * actsN * 2;          // 8.4/4.2 MB
  bf16*  dslot  = (bf16*)(ws + off); off += (size_t)T_TOK * TOPK * H_DIM * 2;   // 16.8 MB

  hipMemsetAsync(counts, 0, 256, stream);

  router_kernel<<<T_TOK, 256, 0, stream>>>(x, rw, sgw, topw, sg, counts, lists);

  if (fullfs) {
    int nsh = (FS_DIM / 64) * 16;   // 1024 shared blocks
    gateup_fused<<<nsh + 3072, 256, 0, stream>>>(
        x, wg, wu, swg, swu, act, acts, lists, counts, nsh, FS_DIM / 64, FS_DIM, 0);
    down_fused<<<512 + 8192, 256, 0, stream>>>(
        act, acts, wd, swd, dslot, out, sg, lists, counts,
        512, FS_DIM, FS_DIM, 0, 0);
  } else {
    int nsh = (FS_HALF / 64) * 16;  // 512 shared blocks
    gateup_fused<<<nsh + 3072, 256, 0, stream>>>(
        x, wg, wu, swg, swu, act, acts, lists, counts, nsh, FS_HALF / 64, FS_HALF, 0);
    down_fused<<<512 + 8192, 256, 0, stream>>>(
        act, acts, wd, swd, dslot, out, sg, lists, counts,
        512, FS_HALF, FS_HALF, 0, 0);
    gateup_fused<<<nsh, 256, 0, stream>>>(
        x, wg, wu, swg, swu, act, acts, lists, counts, nsh, FS_HALF / 64, FS_HALF, FS_HALF);
    down_fused<<<512, 256, 0, stream>>>(
        act, acts, wd, swd, dslot, out, sg, lists, counts,
        512, FS_HALF, FS_HALF, FS_HALF, 1);
  }
  combine_kernel<<<T_TOK, 256, 0, stream>>>(dslot, topw, out);
}

// Round 7
// 380.361 us; speedup vs baseline: 9.1995x; 1.1046x over previous
//
#include <hip/hip_runtime.h>
#include <math.h>

#define T_TOK 1024
#define H_DIM 2048
#define N_EXP 32
#define TOPK  4
#define F_DIM 768
#define FS_DIM 4096
#define FS_HALF 2048

typedef __bf16 bf16;
typedef __attribute__((ext_vector_type(4))) __bf16 bf16x4;
typedef __attribute__((ext_vector_type(8))) __bf16 bf16x8;
typedef __attribute__((ext_vector_type(4))) float f32x4;

// raw barrier: drain ds_writes (lgkm) but let global prefetch loads stay in
// flight across the barrier; sched_barrier(0) pins code motion at the BAR.
#define BAR() do {                                        \
    asm volatile("s_waitcnt lgkmcnt(0)" ::: "memory");    \
    __builtin_amdgcn_s_barrier();                         \
    __builtin_amdgcn_sched_barrier(0);                    \
  } while (0)

// XOR-swizzled LDS offset: rows are 32 bf16 = 64B; swizzle makes A r/w and
// B reads 2-way (free), B 8B-writes 4-way (was 8-way with padded rows).
__device__ __forceinline__ int swz(int row, int colB) {
  return row * 64 + (colB ^ (((row >> 2) & 3) << 4));
}

// ---------------- router: fp32 logits -> softmax -> top4 -> lists ----------------
__global__ __launch_bounds__(256) void router_kernel(
    const float* __restrict__ x, const float* __restrict__ rw,
    const float* __restrict__ sgw,
    float* __restrict__ topw, float* __restrict__ sg,
    int* __restrict__ counts, int* __restrict__ lists)
{
  int t = blockIdx.x; int tid = threadIdx.x;
  int lane = tid & 63, wave = tid >> 6;
  float acc[N_EXP];
  #pragma unroll
  for (int e = 0; e < N_EXP; e++) acc[e] = 0.f;
  float accs = 0.f;
  const float* xr = x + (size_t)t * H_DIM;
  for (int h = tid; h < H_DIM; h += 256) {
    float xv = xr[h];
    accs += xv * sgw[h];
    #pragma unroll
    for (int e = 0; e < N_EXP; e++) acc[e] += xv * rw[e * H_DIM + h];
  }
  __shared__ float red[4][N_EXP];
  __shared__ float reds[4];
  __shared__ float logits[N_EXP];
  #pragma unroll
  for (int e = 0; e < N_EXP; e++) {
    float v = acc[e];
    for (int off = 32; off; off >>= 1) v += __shfl_down(v, off, 64);
    if (lane == 0) red[wave][e] = v;
  }
  {
    float v = accs;
    for (int off = 32; off; off >>= 1) v += __shfl_down(v, off, 64);
    if (lane == 0) reds[wave] = v;
  }
  __syncthreads();
  if (tid < N_EXP) logits[tid] = red[0][tid] + red[1][tid] + red[2][tid] + red[3][tid];
  __syncthreads();
  if (tid == 0) {
    float m = -1e30f;
    #pragma unroll
    for (int e = 0; e < N_EXP; e++) m = fmaxf(m, logits[e]);
    float p[N_EXP];
    #pragma unroll
    for (int e = 0; e < N_EXP; e++) p[e] = expf(logits[e] - m);
    int ids[TOPK]; float vs[TOPK]; float wsum = 0.f;
    #pragma unroll
    for (int k = 0; k < TOPK; k++) {
      int best = 0; float bv = -1.f;
      for (int e = 0; e < N_EXP; e++) {
        if (p[e] > bv) { bv = p[e]; best = e; }
      }
      ids[k] = best; vs[k] = bv; wsum += bv; p[best] = -2.f;
    }
    float inv = 1.f / wsum;
    float sgs = reds[0] + reds[1] + reds[2] + reds[3];
    sg[t] = 1.f / (1.f + expf(-sgs));
    #pragma unroll
    for (int k = 0; k < TOPK; k++) {
      int slot = t * TOPK + k;
      topw[slot] = vs[k] * inv;
      int pos = atomicAdd(&counts[ids[k]], 1);
      lists[ids[k] * T_TOK + pos] = slot;
    }
  }
}

// ------- fused gate/up dual GEMM + SwiGLU, 64x128 tile, BK=32 -------
// swizzled LDS, single-set reg staging, one raw barrier per K-step.
__global__ __launch_bounds__(256, 3) void gateup_fused(
    const float* __restrict__ X,
    const float* __restrict__ wg_, const float* __restrict__ wu_,
    const float* __restrict__ swg, const float* __restrict__ swu,
    bf16* __restrict__ act, bf16* __restrict__ acts,
    const int* __restrict__ lists, const int* __restrict__ counts,
    int n_shared, int sh_fbs, int actsN, int col_off)
{
  int id = blockIdx.x;
  bool gather = id >= n_shared;
  const float *Wg, *Wu; const int* lb = nullptr;
  int count, mt, fb, ldb, Nout; bf16* C;
  if (gather) {
    int g = id - n_shared;
    int j = g >> 3;
    int e = (g & 7) + 8 * (j / 48);   // expert e's 48 blocks share an XCD
    int rr = j % 48;
    fb = (rr % 6) * 128; mt = (rr / 6) * 64;
    count = counts[e]; lb = lists + e * T_TOK;
    Wg = wg_ + (size_t)e * H_DIM * F_DIM;
    Wu = wu_ + (size_t)e * H_DIM * F_DIM;
    ldb = F_DIM; Nout = F_DIM; C = act;
  } else {
    fb = (id % sh_fbs) * 128; mt = (id / sh_fbs) * 64;
    count = T_TOK; ldb = FS_DIM; Nout = actsN;
    Wg = swg + col_off; Wu = swu + col_off;
    C = acts;
  }
  if (mt >= count) return;

  int tid = threadIdx.x;
  int lane = tid & 63, wid = tid >> 6;
  int wr = wid >> 1, wc = wid & 1;   // wave tile: 32 rows x 64 cols

  __shared__ alignas(16) char sA [2][64 * 64];    // [64m][32k] bf16, swizzled
  __shared__ alignas(16) char sBg[2][128 * 64];   // [128n][32k] bf16, swizzled
  __shared__ alignas(16) char sBu[2][128 * 64];

  const float* aptr;
  {
    int r = mt + (tid >> 2);
    int rc = r < count ? r : count - 1;
    int tok = gather ? (lb[rc] >> 2) : rc;
    aptr = X + (size_t)tok * H_DIM + ((tid & 3) << 3);
  }
  int bng = tid & 31;            // n-quad 0..31
  int bk4 = (tid >> 5) << 2;     // k-quad base 0,4,..,28
  const float* bgp = Wg + (size_t)bk4 * ldb + fb + bng * 4;
  const float* bup = Wu + (size_t)bk4 * ldb + fb + bng * 4;

  f32x4 accg[2][4], accu[2][4];
  #pragma unroll
  for (int m = 0; m < 2; m++)
    #pragma unroll
    for (int n = 0; n < 4; n++) {
      accg[m][n] = (f32x4){0.f,0.f,0.f,0.f};
      accu[m][n] = (f32x4){0.f,0.f,0.f,0.f};
    }

  f32x4 av0, av1, gv[4], uv[4];

  #define ISSUE(k0) do {                                              \
    av0 = *(const f32x4*)(aptr + (k0));                               \
    av1 = *(const f32x4*)(aptr + (k0) + 4);                           \
    _Pragma("unroll")                                                 \
    for (int r_ = 0; r_ < 4; r_++) {                                  \
      gv[r_] = *(const f32x4*)(bgp + (size_t)((k0) + r_) * ldb);      \
      uv[r_] = *(const f32x4*)(bup + (size_t)((k0) + r_) * ldb);      \
    } } while (0)

  #define STAGE(b) do {                                               \
    bf16x8 t8;                                                        \
    _Pragma("unroll")                                                 \
    for (int j_ = 0; j_ < 4; j_++) {                                  \
      t8[j_] = (bf16)av0[j_]; t8[4 + j_] = (bf16)av1[j_];             \
    }                                                                 \
    *(bf16x8*)(sA[b] + swz(tid >> 2, (tid & 3) << 4)) = t8;           \
    _Pragma("unroll")                                                 \
    for (int i_ = 0; i_ < 4; i_++) {                                  \
      bf16x4 tg, tu;                                                  \
      tg[0] = (bf16)gv[0][i_]; tg[1] = (bf16)gv[1][i_];               \
      tg[2] = (bf16)gv[2][i_]; tg[3] = (bf16)gv[3][i_];               \
      tu[0] = (bf16)uv[0][i_]; tu[1] = (bf16)uv[1][i_];               \
      tu[2] = (bf16)uv[2][i_]; tu[3] = (bf16)uv[3][i_];               \
      *(bf16x4*)(sBg[b] + swz(bng * 4 + i_, bk4 << 1)) = tg;          \
      *(bf16x4*)(sBu[b] + swz(bng * 4 + i_, bk4 << 1)) = tu;          \
    } } while (0)

  #define MFMA_PHASE(b) do {                                          \
    __builtin_amdgcn_s_setprio(1);                                    \
    int l15 = lane & 15, qB = (lane >> 4) << 4;                       \
    bf16x8 af0 = *(const bf16x8*)(sA[b] + swz(wr * 32 + l15, qB));    \
    bf16x8 af1 = *(const bf16x8*)(sA[b] + swz(wr * 32 + 16 + l15, qB)); \
    _Pragma("unroll")                                                 \
    for (int n_ = 0; n_ < 4; n_++) {                                  \
      int rb = wc * 64 + n_ * 16 + l15;                               \
      bf16x8 bg = *(const bf16x8*)(sBg[b] + swz(rb, qB));             \
      bf16x8 bu = *(const bf16x8*)(sBu[b] + swz(rb, qB));             \
      accg[0][n_] = __builtin_amdgcn_mfma_f32_16x16x32_bf16(af0, bg, accg[0][n_], 0,0,0); \
      accg[1][n_] = __builtin_amdgcn_mfma_f32_16x16x32_bf16(af1, bg, accg[1][n_], 0,0,0); \
      accu[0][n_] = __builtin_amdgcn_mfma_f32_16x16x32_bf16(af0, bu, accu[0][n_], 0,0,0); \
      accu[1][n_] = __builtin_amdgcn_mfma_f32_16x16x32_bf16(af1, bu, accu[1][n_], 0,0,0); \
    }                                                                 \
    __builtin_amdgcn_s_setprio(0);                                    \
  } while (0)

  const int NT = H_DIM / 32;   // 64
  ISSUE(0);
  STAGE(0);
  ISSUE(32);
  BAR();
  for (int t = 0; t < NT - 1; ++t) {
    MFMA_PHASE(t & 1);
    STAGE((t + 1) & 1);
    if (t + 2 < NT) ISSUE((t + 2) * 32);
    BAR();
  }
  MFMA_PHASE((NT - 1) & 1);
  #undef ISSUE
  #undef STAGE
  #undef MFMA_PHASE

  #pragma unroll
  for (int m = 0; m < 2; m++) {
    #pragma unroll
    for (int q = 0; q < 4; q++) {
      int gr = mt + wr * 32 + m * 16 + (lane >> 4) * 4 + q;
      if (gr < count) {
        size_t rowo = (gather ? (size_t)lb[gr] : (size_t)gr) * Nout;
        #pragma unroll
        for (int n = 0; n < 4; n++) {
          float g = accg[m][n][q], u = accu[m][n][q];
          C[rowo + fb + wc * 64 + n * 16 + (lane & 15)] =
              (bf16)(g / (1.f + __expf(-g)) * u);
        }
      }
    }
  }
}

// ------- fused down-proj, 64x128 tile, BK=32, swizzled LDS -------
__global__ __launch_bounds__(256, 4) void down_fused(
    const bf16* __restrict__ act, const bf16* __restrict__ acts,
    const float* __restrict__ wd_, const float* __restrict__ swd,
    bf16* __restrict__ dslot, float* __restrict__ out,
    const float* __restrict__ sg,
    const int* __restrict__ lists, const int* __restrict__ counts,
    int n_shared, int lda_sh, int kd_sh, int swd_off, int accum)
{
  int id = blockIdx.x;
  bool expert = id >= n_shared;
  const bf16* A; const float* W; const int* lb = nullptr;
  int count, mt, nb, Kd, lda;
  if (expert) {
    int g = id - n_shared;
    int j = g >> 3;
    int e = (g & 7) + 8 * (j >> 7);   // expert e's 128 blocks share an XCD
    int rr = j & 127;
    nb = (rr & 15) * 128; mt = (rr >> 4) * 64;
    count = counts[e]; lb = lists + e * T_TOK;
    A = act; lda = F_DIM; Kd = F_DIM;
    W = wd_ + (size_t)e * F_DIM * H_DIM;
  } else {
    nb = (id & 15) * 128; mt = (id >> 4) * 64;
    count = T_TOK; A = acts; lda = lda_sh; Kd = kd_sh;
    W = swd + (size_t)swd_off * H_DIM;
  }
  if (mt >= count) return;

  int tid = threadIdx.x;
  int lane = tid & 63, wid = tid >> 6;
  int wr = wid >> 1, wc = wid & 1;

  __shared__ alignas(16) char sA[2][64 * 64];    // [64m][32k] bf16, swizzled
  __shared__ alignas(16) char sB[2][128 * 64];   // [128n][32k] bf16, swizzled

  const bf16* aptr;
  {
    int r = mt + (tid >> 2);
    int rc = r < count ? r : count - 1;
    int ar = expert ? lb[rc] : rc;
    aptr = A + (size_t)ar * lda + ((tid & 3) << 3);
  }
  int bng = tid & 31;
  int bk4 = (tid >> 5) << 2;
  const float* bptr = W + (size_t)bk4 * H_DIM + nb + bng * 4;

  f32x4 acc[2][4];
  #pragma unroll
  for (int m = 0; m < 2; m++)
    #pragma unroll
    for (int n = 0; n < 4; n++)
      acc[m][n] = (f32x4){0.f,0.f,0.f,0.f};

  f32x4 av, bv[4];

  #define ISSUE(k0) do {                                              \
    av = *(const f32x4*)(aptr + (k0));                                \
    _Pragma("unroll")                                                 \
    for (int r_ = 0; r_ < 4; r_++)                                    \
      bv[r_] = *(const f32x4*)(bptr + (size_t)((k0) + r_) * H_DIM);   \
    } while (0)

  #define STAGE(b) do {                                               \
    *(f32x4*)(sA[b] + swz(tid >> 2, (tid & 3) << 4)) = av;            \
    _Pragma("unroll")                                                 \
    for (int i_ = 0; i_ < 4; i_++) {                                  \
      bf16x4 tb;                                                      \
      tb[0] = (bf16)bv[0][i_]; tb[1] = (bf16)bv[1][i_];               \
      tb[2] = (bf16)bv[2][i_]; tb[3] = (bf16)bv[3][i_];               \
      *(bf16x4*)(sB[b] + swz(bng * 4 + i_, bk4 << 1)) = tb;           \
    } } while (0)

  #define MFMA_PHASE(b) do {                                          \
    __builtin_amdgcn_s_setprio(1);                                    \
    int l15 = lane & 15, qB = (lane >> 4) << 4;                       \
    bf16x8 af0 = *(const bf16x8*)(sA[b] + swz(wr * 32 + l15, qB));    \
    bf16x8 af1 = *(const bf16x8*)(sA[b] + swz(wr * 32 + 16 + l15, qB)); \
    _Pragma("unroll")                                                 \
    for (int n_ = 0; n_ < 4; n_++) {                                  \
      bf16x8 bb = *(const bf16x8*)(sB[b] + swz(wc * 64 + n_ * 16 + l15, qB)); \
      acc[0][n_] = __builtin_amdgcn_mfma_f32_16x16x32_bf16(af0, bb, acc[0][n_], 0,0,0); \
      acc[1][n_] = __builtin_amdgcn_mfma_f32_16x16x32_bf16(af1, bb, acc[1][n_], 0,0,0); \
    }                                                                 \
    __builtin_amdgcn_s_setprio(0);                                    \
  } while (0)

  const int NT = Kd / 32;   // 24, 64 or 128
  ISSUE(0);
  STAGE(0);
  ISSUE(32);
  BAR();
  for (int t = 0; t < NT - 1; ++t) {
    MFMA_PHASE(t & 1);
    STAGE((t + 1) & 1);
    if (t + 2 < NT) ISSUE((t + 2) * 32);
    BAR();
  }
  MFMA_PHASE((NT - 1) & 1);
  #undef ISSUE
  #undef STAGE
  #undef MFMA_PHASE

  #pragma unroll
  for (int m = 0; m < 2; m++) {
    #pragma unroll
    for (int q = 0; q < 4; q++) {
      int gr = mt + wr * 32 + m * 16 + (lane >> 4) * 4 + q;
      if (gr < count) {
        #pragma unroll
        for (int n = 0; n < 4; n++) {
          int col = nb + wc * 64 + n * 16 + (lane & 15);
          if (expert) {
            dslot[(size_t)lb[gr] * H_DIM + col] = (bf16)acc[m][n][q];
          } else if (!accum) {
            out[(size_t)gr * H_DIM + col] = sg[gr] * acc[m][n][q];
          } else {
            out[(size_t)gr * H_DIM + col] += sg[gr] * acc[m][n][q];
          }
        }
      }
    }
  }
}

// ---------------- combine: out += sum_k topw*dslot ----------------
__global__ __launch_bounds__(256) void combine_kernel(
    const bf16* __restrict__ dslot, const float* __restrict__ topw,
    float* __restrict__ out)
{
  int t = blockIdx.x;
  int h = threadIdx.x * 8;
  float w0 = topw[t * 4 + 0], w1 = topw[t * 4 + 1];
  float w2 = topw[t * 4 + 2], w3 = topw[t * 4 + 3];
  bf16x8 a0 = *(const bf16x8*)&dslot[(size_t)(t * 4 + 0) * H_DIM + h];
  bf16x8 a1 = *(const bf16x8*)&dslot[(size_t)(t * 4 + 1) * H_DIM + h];
  bf16x8 a2 = *(const bf16x8*)&dslot[(size_t)(t * 4 + 2) * H_DIM + h];
  bf16x8 a3 = *(const bf16x8*)&dslot[(size_t)(t * 4 + 3) * H_DIM + h];
  f32x4 o0 = *(f32x4*)&out[(size_t)t * H_DIM + h];
  f32x4 o1 = *(f32x4*)&out[(size_t)t * H_DIM + h + 4];
  float o[8] = {o0[0], o0[1], o0[2], o0[3], o1[0], o1[1], o1[2], o1[3]};
  #pragma unroll
  for (int j = 0; j < 8; j++)
    o[j] += w0 * (float)a0[j] + w1 * (float)a1[j] + w2 * (float)a2[j]
          + w3 * (float)a3[j];
  *(f32x4*)&out[(size_t)t * H_DIM + h]     = (f32x4){o[0], o[1], o[2], o[3]};
  *(f32x4*)&out[(size_t)t * H_DIM + h + 4] = (f32x4){o[4], o[5], o[6], o[7]};
}

extern "C" void kernel_launch(void* const* d_in, const int* in_sizes, int n_in,
                              void* d_out, int out_size, void* d_ws, size_t ws_size,
                              hipStream_t stream) {
  const float* x   = (const float*)d_in[0];
  const float* rw  = (const float*)d_in[1];
  const float* wg  = (const float*)d_in[2];
  const float* wu  = (const float*)d_in[3];
  const float* wd  = (const float*)d_in[4];
  const float* swg = (const float*)d_in[5];
  const float* swu = (const float*)d_in[6];
  const float* swd = (const float*)d_in[7];
  const float* sgw = (const float*)d_in[8];
  float* out = (float*)d_out;
  char* ws = (char*)d_ws;

  // full-FS path needs 31.61 MB of ws; halves path 27.4 MB (34 MB overflowed
  // in round 3 -> replay divergence; gate at runtime)
  bool fullfs = ws_size >= (size_t)31700000;
  size_t actsN = fullfs ? FS_DIM : FS_HALF;

  size_t off = 0;
  int*   counts = (int*)(ws + off); off += 256;
  int*   lists  = (int*)(ws + off); off += (size_t)N_EXP * T_TOK * 4;
  float* topw   = (float*)(ws + off); off += (size_t)T_TOK * TOPK * 4;
  float* sg     = (float*)(ws + off); off += (size_t)T_TOK * 4;
  bf16*  act    = (bf16*)(ws + off); off += (size_t)T_TOK * TOPK * F_DIM * 2;
  bf16*  acts   = (bf16*)(ws + off); off += (size_t)T_TOK * actsN * 2;
  bf16*  dslot  = (bf16*)(ws + off); off += (size_t)T_TOK * TOPK * H_DIM * 2;

  hipMemsetAsync(counts, 0, 256, stream);

  router_kernel<<<T_TOK, 256, 0, stream>>>(x, rw, sgw, topw, sg, counts, lists);

  const int EXP_GU = N_EXP * 48;    // 1536
  const int EXP_DN = N_EXP * 128;   // 4096
  if (fullfs) {
    int nsh = 16 * (FS_DIM / 128);  // 512
    gateup_fused<<<nsh + EXP_GU, 256, 0, stream>>>(
        x, wg, wu, swg, swu, act, acts, lists, counts, nsh, FS_DIM / 128, FS_DIM, 0);
    down_fused<<<256 + EXP_DN, 256, 0, stream>>>(
        act, acts, wd, swd, dslot, out, sg, lists, counts,
        256, FS_DIM, FS_DIM, 0, 0);
  } else {
    int nsh = 16 * (FS_HALF / 128); // 256
    gateup_fused<<<nsh + EXP_GU, 256, 0, stream>>>(
        x, wg, wu, swg, swu, act, acts, lists, counts, nsh, FS_HALF / 128, FS_HALF, 0);
    down_fused<<<256 + EXP_DN, 256, 0, stream>>>(
        act, acts, wd, swd, dslot, out, sg, lists, counts,
        256, FS_HALF, FS_HALF, 0, 0);
    gateup_fused<<<nsh, 256, 0, stream>>>(
        x, wg, wu, swg, swu, act, acts, lists, counts, nsh, FS_HALF / 128, FS_HALF, FS_HALF);
    down_fused<<<256, 256, 0, stream>>>(
        act, acts, wd, swd, dslot, out, sg, lists, counts,
        256, FS_HALF, FS_HALF, FS_HALF, 1);
  }
  combine_kernel<<<T_TOK, 256, 0, stream>>>(dslot, topw, out);
}